// Round 3
// baseline (611.642 us; speedup 1.0000x reference)
//
#include <hip/hip_runtime.h>
#include <stdint.h>

#define L_SEQ 2048
#define DMODEL 1024
#define NHEAD 16
#define HDIM 64
#define BATCH 2

typedef __attribute__((ext_vector_type(8))) short bf16x8;
typedef __attribute__((ext_vector_type(4))) float f32x4;

#define MFMA(a, b, c) __builtin_amdgcn_mfma_f32_16x16x32_bf16((a), (b), (c), 0, 0, 0)

#if __has_builtin(__builtin_amdgcn_exp2f)
#define EXP2(x) __builtin_amdgcn_exp2f(x)
#else
#define EXP2(x) exp2f(x)
#endif

__device__ __forceinline__ unsigned short f2bf(float f) {
    unsigned int x = __float_as_uint(f);
    unsigned int r = (x + 0x7fffu + ((x >> 16) & 1u)) >> 16;
    return (unsigned short)r;
}
__device__ __forceinline__ float bf2f(unsigned short h) {
    return __uint_as_float(((unsigned int)h) << 16);
}

// ---------------------------------------------------------------------------
// Tiny prep 1: pack mask (int32, B*L) into uint64 bitmasks, 1 bit per key.
// ---------------------------------------------------------------------------
__global__ void maskpack_kernel(const int* __restrict__ mask,
                                unsigned long long* __restrict__ mbits) {
    const int w = blockIdx.x;
    const unsigned long long bal = __ballot(mask[w * 64 + threadIdx.x] != 0);
    if (threadIdx.x == 0) mbits[w] = bal;
}

// ---------------------------------------------------------------------------
// Tiny prep 2: split Wo (fp32 DxD) into hi/lo bf16 planes.
// ---------------------------------------------------------------------------
__global__ void wsplit_kernel(const float* __restrict__ W,
                              unsigned short* __restrict__ hi,
                              unsigned short* __restrict__ lo) {
    const int i = (blockIdx.x * 256 + threadIdx.x) * 4;
    const float4 v = *(const float4*)(W + i);
    const float f[4] = {v.x, v.y, v.z, v.w};
    union { unsigned short s[4]; uint2 u; } h, l;
#pragma unroll
    for (int r = 0; r < 4; ++r) {
        h.s[r] = f2bf(f[r]);
        l.s[r] = f2bf(f[r] - bf2f(h.s[r]));
    }
    *(uint2*)&hi[i] = h.u;
    *(uint2*)&lo[i] = l.u;
}

// ---------------------------------------------------------------------------
// Kernel A (fused z=0,1,2): C = X @ W^T + bias, fp32 in, bf16 MFMA.
// z<2 (Q,K): RoPE in epilogue, write bf16 [b,n,l,h].
// z==2 (V): write bf16 TRANSPOSED [b,n,h,l] (b64 packed along l).
// 128x128 tile, BK=32, 4 waves 2x2, 64x64 per wave.
// ---------------------------------------------------------------------------
__global__ __launch_bounds__(256) void qkv_kernel(
    const float* __restrict__ Xq, const float* __restrict__ Xk, const float* __restrict__ Xv,
    const float* __restrict__ Wq, const float* __restrict__ Wk, const float* __restrict__ Wv,
    const float* __restrict__ bq, const float* __restrict__ bk, const float* __restrict__ bv,
    unsigned short* __restrict__ Qd, unsigned short* __restrict__ Kd,
    unsigned short* __restrict__ Vd)
{
    const int z = blockIdx.z;
    const float* X    = (z == 0) ? Xq : (z == 1) ? Xk : Xv;
    const float* W    = (z == 0) ? Wq : (z == 1) ? Wk : Wv;
    const float* bias = (z == 0) ? bq : (z == 1) ? bk : bv;

    __shared__ __align__(16) unsigned short As[128 * 40];  // +8 pad
    __shared__ __align__(16) unsigned short Bs[128 * 40];

    const int tid  = threadIdx.x;
    const int wave = tid >> 6, lane = tid & 63;
    const int ml = lane & 15, kq = lane >> 4;
    const int m0 = blockIdx.y * 128, n0 = blockIdx.x * 128;
    const int wm = (wave & 1) * 64, wn = (wave >> 1) * 64;

    f32x4 acc[4][4];
#pragma unroll
    for (int i = 0; i < 4; ++i)
#pragma unroll
        for (int j = 0; j < 4; ++j) acc[i][j] = (f32x4){0.f, 0.f, 0.f, 0.f};

    const int srow = tid >> 2;       // 0..63
    const int c8   = (tid & 3) * 8;  // 0,8,16,24

    for (int kc = 0; kc < DMODEL; kc += 32) {
#pragma unroll
        for (int p = 0; p < 2; ++p) {
            const int row = srow + 64 * p;
            const float* xa = X + (size_t)(m0 + row) * DMODEL + kc + c8;
            const float4 a0 = *(const float4*)xa;
            const float4 a1 = *(const float4*)(xa + 4);
            union { unsigned short s[8]; uint4 u; } ua;
            ua.s[0] = f2bf(a0.x); ua.s[1] = f2bf(a0.y); ua.s[2] = f2bf(a0.z); ua.s[3] = f2bf(a0.w);
            ua.s[4] = f2bf(a1.x); ua.s[5] = f2bf(a1.y); ua.s[6] = f2bf(a1.z); ua.s[7] = f2bf(a1.w);
            *(uint4*)&As[row * 40 + c8] = ua.u;
            const float* xb = W + (size_t)(n0 + row) * DMODEL + kc + c8;
            const float4 b0 = *(const float4*)xb;
            const float4 b1 = *(const float4*)(xb + 4);
            union { unsigned short s[8]; uint4 u; } ub;
            ub.s[0] = f2bf(b0.x); ub.s[1] = f2bf(b0.y); ub.s[2] = f2bf(b0.z); ub.s[3] = f2bf(b0.w);
            ub.s[4] = f2bf(b1.x); ub.s[5] = f2bf(b1.y); ub.s[6] = f2bf(b1.z); ub.s[7] = f2bf(b1.w);
            *(uint4*)&Bs[row * 40 + c8] = ub.u;
        }
        __syncthreads();

        bf16x8 af[4], bfr[4];
#pragma unroll
        for (int i = 0; i < 4; ++i)
            af[i] = *(const bf16x8*)&As[(wm + i * 16 + ml) * 40 + kq * 8];
#pragma unroll
        for (int j = 0; j < 4; ++j)
            bfr[j] = *(const bf16x8*)&Bs[(wn + j * 16 + ml) * 40 + kq * 8];
#pragma unroll
        for (int i = 0; i < 4; ++i)
#pragma unroll
            for (int j = 0; j < 4; ++j)
                acc[i][j] = MFMA(af[i], bfr[j], acc[i][j]);
        __syncthreads();
    }

    if (z < 2) {
        unsigned short* dst = (z == 0) ? Qd : Kd;
        // RoPE epilogue (C layout: row=(b,l), col=feature), shfl_xor pairs.
#pragma unroll
        for (int jt = 0; jt < 4; ++jt) {
            const int col = n0 + wn + jt * 16 + ml;
            const float bv = bias[col];
            const int nh = col >> 6, hh = col & 63;
            const float inv_freq = powf(10000.0f, -(float)(hh & 62) * (1.0f / 64.0f));
#pragma unroll
            for (int it = 0; it < 4; ++it) {
#pragma unroll
                for (int r = 0; r < 4; ++r) {
                    const int row = m0 + wm + it * 16 + kq * 4 + r;
                    const int bb = row >> 11, ll = row & 2047;
                    const float v = acc[it][jt][r] + bv;
                    const float partner = __shfl_xor(v, 1);
                    float sn, cs;
                    sincosf((float)ll * inv_freq, &sn, &cs);
                    const float res = (hh & 1) ? fmaf(v, cs, partner * sn)
                                               : fmaf(v, cs, -partner * sn);
                    dst[(((size_t)(bb * NHEAD + nh) * L_SEQ + ll) << 6) + hh] = f2bf(res);
                }
            }
        }
    } else {
        // V: write transposed [b,n,h,l], pack 4 consecutive l per lane (b64).
#pragma unroll
        for (int jt = 0; jt < 4; ++jt) {
            const int col = n0 + wn + jt * 16 + ml;
            const float bv = bias[col];
            const int nh = col >> 6, hh = col & 63;
#pragma unroll
            for (int it = 0; it < 4; ++it) {
                const int rb = m0 + wm + it * 16 + kq * 4;
                const int bb = rb >> 11, ll = rb & 2047;
                union { unsigned short s[4]; uint2 u; } pk;
#pragma unroll
                for (int r = 0; r < 4; ++r) pk.s[r] = f2bf(acc[it][jt][r] + bv);
                *(uint2*)&Vd[(((size_t)bb * NHEAD + nh) * HDIM + hh) * L_SEQ + ll] = pk.u;
            }
        }
    }
}

// ---------------------------------------------------------------------------
// Kernel B: flash attention, S^T / O^T formulation.
// Block = 128 q-rows of one (b,head); 4 waves x 32 q; 64-key tiles.
// Ks/Vs: 64x64 bf16, XOR-swizzled chunks (chunk ^= row&7) -> <=2-way banks.
// Softmax per-lane in log2 domain; only 4 shuffles per (qt,tile).
// Output: hi/lo bf16 planes of O, coalesced via per-wave LDS transpose.
// ---------------------------------------------------------------------------
__global__ __launch_bounds__(256) void attn_kernel(
    const unsigned short* __restrict__ Qr, const unsigned short* __restrict__ Kr,
    const unsigned short* __restrict__ Vt, const unsigned long long* __restrict__ mbits,
    unsigned short* __restrict__ AOhi, unsigned short* __restrict__ AOlo)
{
    __shared__ __align__(16) unsigned short Ks[64 * 64];
    __shared__ __align__(16) unsigned short Vs[64 * 64];
    __shared__ __align__(16) unsigned short Ps[4 * 32 * 72];  // per-wave P / epilogue scratch

    const int tid  = threadIdx.x;
    const int wave = tid >> 6, lane = tid & 63;
    const int ml = lane & 15, kq = lane >> 4;

    // XCD swizzle: 16 q-blocks of the same (b,head) land on the same XCD.
    const int id = blockIdx.x;
    const int xcd = id & 7, slot = id >> 3;
    const int bh = xcd * 4 + (slot & 3);
    const int qb = slot >> 2;
    const int b = bh >> 4, nh = bh & 15;
    const int q0 = qb * 128;

    const unsigned short* Qp = Qr + (size_t)bh * L_SEQ * HDIM;
    const unsigned short* Kp = Kr + (size_t)bh * L_SEQ * HDIM;
    const unsigned short* Vp = Vt + (size_t)bh * HDIM * L_SEQ;

    const int wq = wave * 32;
    bf16x8 qf[2][2];  // [qt][k-chunk]
#pragma unroll
    for (int qt = 0; qt < 2; ++qt)
#pragma unroll
        for (int c = 0; c < 2; ++c)
            qf[qt][c] = *(const bf16x8*)(Qp + (size_t)(q0 + wq + qt * 16 + ml) * HDIM + c * 32 + kq * 8);

    float m2[2] = {-1e30f, -1e30f};
    float li[2] = {0.f, 0.f};
    f32x4 o[2][4];
#pragma unroll
    for (int qt = 0; qt < 2; ++qt)
#pragma unroll
        for (int ht = 0; ht < 4; ++ht) o[qt][ht] = (f32x4){0.f, 0.f, 0.f, 0.f};

    unsigned short* Pw = &Ps[wave * 32 * 72];
    const int srow = tid >> 2;          // 0..63
    const int c0   = (tid & 3) * 2;     // chunk pair
    const float SC = 0.045084230f;      // log2(e) / 32

    for (int kt = 0; kt < L_SEQ / 64; ++kt) {
        __syncthreads();
        {   // stage K [key][h] and V^T [h][key], XOR-swizzled
            const unsigned short* kg = Kp + (size_t)(kt * 64 + srow) * HDIM + c0 * 8;
            const uint4 k0 = *(const uint4*)kg;
            const uint4 k1 = *(const uint4*)(kg + 8);
            *(uint4*)&Ks[srow * 64 + ((c0 ^ (srow & 7)) << 3)]       = k0;
            *(uint4*)&Ks[srow * 64 + (((c0 + 1) ^ (srow & 7)) << 3)] = k1;
            const unsigned short* vg = Vp + (size_t)srow * L_SEQ + kt * 64 + c0 * 8;
            const uint4 v0 = *(const uint4*)vg;
            const uint4 v1 = *(const uint4*)(vg + 8);
            *(uint4*)&Vs[srow * 64 + ((c0 ^ (srow & 7)) << 3)]       = v0;
            *(uint4*)&Vs[srow * 64 + (((c0 + 1) ^ (srow & 7)) << 3)] = v1;
        }
        __syncthreads();

        const unsigned long long mw = mbits[b * 32 + kt];

        // S^T = K * Q^T : [key 64][q 32]; C layout: row=key(kq*4+r), col=q(ml)
        f32x4 st[4][2];
#pragma unroll
        for (int nt = 0; nt < 4; ++nt) {
            const int krow = (nt * 16 + ml) * 64;
            const bf16x8 kf0 = *(const bf16x8*)&Ks[krow + (((0 + kq) ^ (ml & 7)) << 3)];
            const bf16x8 kf1 = *(const bf16x8*)&Ks[krow + (((4 + kq) ^ (ml & 7)) << 3)];
#pragma unroll
            for (int qt = 0; qt < 2; ++qt) {
                f32x4 c = (f32x4){0.f, 0.f, 0.f, 0.f};
                c = MFMA(kf0, qf[qt][0], c);
                c = MFMA(kf1, qf[qt][1], c);
                st[nt][qt] = c;
            }
        }

        // online softmax (log2 domain), P -> LDS (b64 packed)
        float alpha[2];
#pragma unroll
        for (int qt = 0; qt < 2; ++qt) {
            float sv[4][4];
#pragma unroll
            for (int nt = 0; nt < 4; ++nt) {
                const unsigned int nib =
                    ((unsigned int)(mw >> (nt * 16 + kq * 4))) & 0xFu;
#pragma unroll
                for (int r = 0; r < 4; ++r)
                    sv[nt][r] = (nib & (1u << r)) ? -1.0e9f : st[nt][qt][r] * SC;
            }
            float rm = sv[0][0];
#pragma unroll
            for (int nt = 0; nt < 4; ++nt)
#pragma unroll
                for (int r = 0; r < 4; ++r) rm = fmaxf(rm, sv[nt][r]);
            rm = fmaxf(rm, __shfl_xor(rm, 16));
            rm = fmaxf(rm, __shfl_xor(rm, 32));
            const float m2n = fmaxf(m2[qt], rm);
            alpha[qt] = EXP2(m2[qt] - m2n);
            m2[qt] = m2n;
            float rs = 0.f;
#pragma unroll
            for (int nt = 0; nt < 4; ++nt) {
                float p[4];
#pragma unroll
                for (int r = 0; r < 4; ++r) {
                    p[r] = EXP2(sv[nt][r] - m2n);
                    rs += p[r];
                }
                union { unsigned short s[4]; uint2 u; } pk;
#pragma unroll
                for (int r = 0; r < 4; ++r) pk.s[r] = f2bf(p[r]);
                *(uint2*)&Pw[(qt * 16 + ml) * 72 + nt * 16 + kq * 4] = pk.u;
            }
            rs += __shfl_xor(rs, 16);
            rs += __shfl_xor(rs, 32);
            li[qt] = li[qt] * alpha[qt] + rs;
        }

        // O^T += V^T * P : A=V^T frags, B=P frags; no cross-lane alpha needed.
        bf16x8 vf[4][2];
#pragma unroll
        for (int ht = 0; ht < 4; ++ht) {
            const int vrow = (ht * 16 + ml) * 64;
            vf[ht][0] = *(const bf16x8*)&Vs[vrow + (((0 + kq) ^ (ml & 7)) << 3)];
            vf[ht][1] = *(const bf16x8*)&Vs[vrow + (((4 + kq) ^ (ml & 7)) << 3)];
        }
#pragma unroll
        for (int qt = 0; qt < 2; ++qt) {
            const bf16x8 pf0 = *(const bf16x8*)&Pw[(qt * 16 + ml) * 72 + 0 + kq * 8];
            const bf16x8 pf1 = *(const bf16x8*)&Pw[(qt * 16 + ml) * 72 + 32 + kq * 8];
#pragma unroll
            for (int ht = 0; ht < 4; ++ht) {
                f32x4 a = o[qt][ht];
#pragma unroll
                for (int r = 0; r < 4; ++r) a[r] *= alpha[qt];
                a = MFMA(vf[ht][0], pf0, a);
                a = MFMA(vf[ht][1], pf1, a);
                o[qt][ht] = a;
            }
        }
    }

    // Epilogue: O^T lane holds (h = ht*16+kq*4+r, q = qt*16+ml).
    // Per-wave LDS transpose through Pw -> coalesced global stores.
    // Each lane then owns q=lane>>1, h-half=(lane&1)*32 .. +32 = 4x uint4.
    const float inv[2] = {1.f / li[0], 1.f / li[1]};
    const int qr = lane >> 1, half = lane & 1;
    const size_t gbase = ((size_t)b * L_SEQ + q0 + wq + qr) * DMODEL + nh * 64 + half * 32;

    // hi plane
#pragma unroll
    for (int qt = 0; qt < 2; ++qt)
#pragma unroll
        for (int ht = 0; ht < 4; ++ht) {
            union { unsigned short s[4]; uint2 u; } pk;
#pragma unroll
            for (int r = 0; r < 4; ++r) pk.s[r] = f2bf(o[qt][ht][r] * inv[qt]);
            *(uint2*)&Pw[(qt * 16 + ml) * 72 + ht * 16 + kq * 4] = pk.u;
        }
    {
        const uint4 d0 = *(const uint4*)&Pw[qr * 72 + half * 32];
        const uint4 d1 = *(const uint4*)&Pw[qr * 72 + half * 32 + 8];
        const uint4 d2 = *(const uint4*)&Pw[qr * 72 + half * 32 + 16];
        const uint4 d3 = *(const uint4*)&Pw[qr * 72 + half * 32 + 24];
        *(uint4*)&AOhi[gbase]      = d0;
        *(uint4*)&AOhi[gbase + 8]  = d1;
        *(uint4*)&AOhi[gbase + 16] = d2;
        *(uint4*)&AOhi[gbase + 24] = d3;
    }
    // lo plane
#pragma unroll
    for (int qt = 0; qt < 2; ++qt)
#pragma unroll
        for (int ht = 0; ht < 4; ++ht) {
            union { unsigned short s[4]; uint2 u; } pk;
#pragma unroll
            for (int r = 0; r < 4; ++r) {
                const float v = o[qt][ht][r] * inv[qt];
                const unsigned short h = f2bf(v);
                pk.s[r] = f2bf(v - bf2f(h));
            }
            *(uint2*)&Pw[(qt * 16 + ml) * 72 + ht * 16 + kq * 4] = pk.u;
        }
    {
        const uint4 d0 = *(const uint4*)&Pw[qr * 72 + half * 32];
        const uint4 d1 = *(const uint4*)&Pw[qr * 72 + half * 32 + 8];
        const uint4 d2 = *(const uint4*)&Pw[qr * 72 + half * 32 + 16];
        const uint4 d3 = *(const uint4*)&Pw[qr * 72 + half * 32 + 24];
        *(uint4*)&AOlo[gbase]      = d0;
        *(uint4*)&AOlo[gbase + 8]  = d1;
        *(uint4*)&AOlo[gbase + 16] = d2;
        *(uint4*)&AOlo[gbase + 24] = d3;
    }
}

// ---------------------------------------------------------------------------
// Kernel C: out = AO @ Wo^T + bo, 3-term bf16-split (hi*hi + lo*hi + hi*lo).
// All operands pre-split bf16 planes -> pure b128 staging, no conversion.
// ---------------------------------------------------------------------------
__global__ __launch_bounds__(256) void oproj_kernel(
    const unsigned short* __restrict__ Ahi_g, const unsigned short* __restrict__ Alo_g,
    const unsigned short* __restrict__ Whi_g, const unsigned short* __restrict__ Wlo_g,
    const float* __restrict__ bias, float* __restrict__ out)
{
    __shared__ __align__(16) unsigned short Ah[128 * 40], Al[128 * 40];
    __shared__ __align__(16) unsigned short Bh[128 * 40], Bl[128 * 40];

    const int tid  = threadIdx.x;
    const int wave = tid >> 6, lane = tid & 63;
    const int ml = lane & 15, kq = lane >> 4;
    const int m0 = blockIdx.y * 128, n0 = blockIdx.x * 128;
    const int wm = (wave & 1) * 64, wn = (wave >> 1) * 64;

    f32x4 acc[4][4];
#pragma unroll
    for (int i = 0; i < 4; ++i)
#pragma unroll
        for (int j = 0; j < 4; ++j) acc[i][j] = (f32x4){0.f, 0.f, 0.f, 0.f};

    const int srow = tid >> 2;
    const int c8   = (tid & 3) * 8;

    for (int kc = 0; kc < DMODEL; kc += 32) {
#pragma unroll
        for (int p = 0; p < 2; ++p) {
            const int row = srow + 64 * p;
            const size_t ga = (size_t)(m0 + row) * DMODEL + kc + c8;
            *(uint4*)&Ah[row * 40 + c8] = *(const uint4*)(Ahi_g + ga);
            *(uint4*)&Al[row * 40 + c8] = *(const uint4*)(Alo_g + ga);
            const size_t gb = (size_t)(n0 + row) * DMODEL + kc + c8;
            *(uint4*)&Bh[row * 40 + c8] = *(const uint4*)(Whi_g + gb);
            *(uint4*)&Bl[row * 40 + c8] = *(const uint4*)(Wlo_g + gb);
        }
        __syncthreads();

        bf16x8 ah[4], al[4];
#pragma unroll
        for (int i = 0; i < 4; ++i) {
            ah[i] = *(const bf16x8*)&Ah[(wm + i * 16 + ml) * 40 + kq * 8];
            al[i] = *(const bf16x8*)&Al[(wm + i * 16 + ml) * 40 + kq * 8];
        }
#pragma unroll
        for (int j = 0; j < 4; ++j) {
            const bf16x8 bh_ = *(const bf16x8*)&Bh[(wn + j * 16 + ml) * 40 + kq * 8];
            const bf16x8 bl_ = *(const bf16x8*)&Bl[(wn + j * 16 + ml) * 40 + kq * 8];
#pragma unroll
            for (int i = 0; i < 4; ++i) {
                acc[i][j] = MFMA(ah[i], bh_, acc[i][j]);
                acc[i][j] = MFMA(al[i], bh_, acc[i][j]);
                acc[i][j] = MFMA(ah[i], bl_, acc[i][j]);
            }
        }
        __syncthreads();
    }

#pragma unroll
    for (int jt = 0; jt < 4; ++jt) {
        const int col = n0 + wn + jt * 16 + ml;
        const float bv = bias[col];
#pragma unroll
        for (int it = 0; it < 4; ++it)
#pragma unroll
            for (int r = 0; r < 4; ++r) {
                const int row = m0 + wm + it * 16 + kq * 4 + r;
                out[(size_t)row * DMODEL + col] = acc[it][jt][r] + bv;
            }
    }
}

extern "C" void kernel_launch(void* const* d_in, const int* in_sizes, int n_in,
                              void* d_out, int out_size, void* d_ws, size_t ws_size,
                              hipStream_t stream)
{
    (void)in_sizes; (void)n_in; (void)out_size; (void)ws_size;
    const float* q    = (const float*)d_in[0];
    const float* k    = (const float*)d_in[1];
    const float* v    = (const float*)d_in[2];
    const int*   mask = (const int*)d_in[3];
    const float* Wq   = (const float*)d_in[4];
    const float* bq   = (const float*)d_in[5];
    const float* Wk   = (const float*)d_in[6];
    const float* bk   = (const float*)d_in[7];
    const float* Wv   = (const float*)d_in[8];
    const float* bv   = (const float*)d_in[9];
    const float* Wo   = (const float*)d_in[10];
    const float* bo   = (const float*)d_in[11];
    float* out = (float*)d_out;

    const size_t HE = (size_t)BATCH * NHEAD * L_SEQ * HDIM;  // 4,194,304 elems
    unsigned short* Qr   = (unsigned short*)d_ws;
    unsigned short* Kr   = Qr + HE;
    unsigned short* Vt   = Kr + HE;
    unsigned short* AOhi = Vt + HE;
    unsigned short* AOlo = AOhi + HE;
    unsigned short* Whi  = AOlo + HE;                         // 1M elems
    unsigned short* Wlo  = Whi + (size_t)DMODEL * DMODEL;
    unsigned long long* mbits = (unsigned long long*)(Wlo + (size_t)DMODEL * DMODEL);
    // total ws: 5*8MB + 2*2MB + 512B = ~44MB

    maskpack_kernel<<<dim3(BATCH * L_SEQ / 64), dim3(64), 0, stream>>>(mask, mbits);
    wsplit_kernel<<<dim3(DMODEL * DMODEL / 1024), dim3(256), 0, stream>>>(Wo, Whi, Wlo);

    dim3 blk(256);
    dim3 g1(DMODEL / 128, (BATCH * L_SEQ) / 128, 3);  // 8 x 32 x 3 = 768 blocks
    qkv_kernel<<<g1, blk, 0, stream>>>(q, k, v, Wq, Wk, Wv, bq, bk, bv, Qr, Kr, Vt);

    attn_kernel<<<dim3(512), blk, 0, stream>>>(Qr, Kr, Vt, mbits, AOhi, AOlo);

    dim3 g3(DMODEL / 128, (BATCH * L_SEQ) / 128);     // 8 x 32
    oproj_kernel<<<g3, blk, 0, stream>>>(AOhi, AOlo, Whi, Wlo, bo, out);
}

// Round 4
// 342.169 us; speedup vs baseline: 1.7875x; 1.7875x over previous
//
#include <hip/hip_runtime.h>
#include <stdint.h>

#define L_SEQ 2048
#define DMODEL 1024
#define NHEAD 16
#define HDIM 64
#define BATCH 2

typedef __attribute__((ext_vector_type(8))) short bf16x8;
typedef __attribute__((ext_vector_type(4))) float f32x4;

#define MFMA(a, b, c) __builtin_amdgcn_mfma_f32_16x16x32_bf16((a), (b), (c), 0, 0, 0)

#if __has_builtin(__builtin_amdgcn_exp2f)
#define EXP2(x) __builtin_amdgcn_exp2f(x)
#else
#define EXP2(x) exp2f(x)
#endif

__device__ __forceinline__ unsigned short f2bf(float f) {
    unsigned int x = __float_as_uint(f);
    unsigned int r = (x + 0x7fffu + ((x >> 16) & 1u)) >> 16;
    return (unsigned short)r;
}
__device__ __forceinline__ float bf2f(unsigned short h) {
    return __uint_as_float(((unsigned int)h) << 16);
}

// ---------------------------------------------------------------------------
// Tiny prep 1: pack mask (int32, B*L) into uint64 bitmasks, 1 bit per key.
// ---------------------------------------------------------------------------
__global__ void maskpack_kernel(const int* __restrict__ mask,
                                unsigned long long* __restrict__ mbits) {
    const int w = blockIdx.x;
    const unsigned long long bal = __ballot(mask[w * 64 + threadIdx.x] != 0);
    if (threadIdx.x == 0) mbits[w] = bal;
}

// ---------------------------------------------------------------------------
// Tiny prep 2: split Wo (fp32 DxD) into hi/lo bf16 planes.
// ---------------------------------------------------------------------------
__global__ void wsplit_kernel(const float* __restrict__ W,
                              unsigned short* __restrict__ hi,
                              unsigned short* __restrict__ lo) {
    const int i = (blockIdx.x * 256 + threadIdx.x) * 4;
    const float4 v = *(const float4*)(W + i);
    const float f[4] = {v.x, v.y, v.z, v.w};
    union { unsigned short s[4]; uint2 u; } h, l;
#pragma unroll
    for (int r = 0; r < 4; ++r) {
        h.s[r] = f2bf(f[r]);
        l.s[r] = f2bf(f[r] - bf2f(h.s[r]));
    }
    *(uint2*)&hi[i] = h.u;
    *(uint2*)&lo[i] = l.u;
}

// ---------------------------------------------------------------------------
// Tiny prep 3: RoPE table, float2(cos, sin) per (l, h). 1 MB, L3-resident.
// tab[l*64+h] = (cos(l * invf), sin(l * invf)), invf = 10000^-((h&62)/64).
// Keeps all transcendental calls OUT of the hot GEMM epilogue (they force
// accumulator spills to scratch: R3's 1.5 GB WRITE_SIZE, MfmaUtil 2.7%).
// ---------------------------------------------------------------------------
__global__ void rope_table_kernel(float2* __restrict__ tab) {
    const int idx = blockIdx.x * 256 + threadIdx.x;   // 0 .. 131071
    const int l = idx >> 6, h = idx & 63;
    const float invf = powf(10000.0f, -(float)(h & 62) * (1.0f / 64.0f));
    float sn, cs;
    sincosf((float)l * invf, &sn, &cs);
    tab[idx] = make_float2(cs, sn);
}

// ---------------------------------------------------------------------------
// Kernel A (fused z=0,1,2): C = X @ W^T + bias, fp32 in, bf16 MFMA.
// z<2 (Q,K): RoPE via table lookup in epilogue, write bf16 [b,n,l,h].
// z==2 (V): write bf16 TRANSPOSED [b,n,h,l] (b64 packed along l).
// 128x128 tile, BK=32, 4 waves 2x2, 64x64 per wave. NO libm calls anywhere.
// ---------------------------------------------------------------------------
__global__ __launch_bounds__(256) void qkv_kernel(
    const float* __restrict__ Xq, const float* __restrict__ Xk, const float* __restrict__ Xv,
    const float* __restrict__ Wq, const float* __restrict__ Wk, const float* __restrict__ Wv,
    const float* __restrict__ bq, const float* __restrict__ bk, const float* __restrict__ bv,
    const float2* __restrict__ ropetab,
    unsigned short* __restrict__ Qd, unsigned short* __restrict__ Kd,
    unsigned short* __restrict__ Vd)
{
    const int z = blockIdx.z;
    const float* X    = (z == 0) ? Xq : (z == 1) ? Xk : Xv;
    const float* W    = (z == 0) ? Wq : (z == 1) ? Wk : Wv;
    const float* bias = (z == 0) ? bq : (z == 1) ? bk : bv;

    __shared__ __align__(16) unsigned short As[128 * 40];  // +8 pad
    __shared__ __align__(16) unsigned short Bs[128 * 40];

    const int tid  = threadIdx.x;
    const int wave = tid >> 6, lane = tid & 63;
    const int ml = lane & 15, kq = lane >> 4;
    const int m0 = blockIdx.y * 128, n0 = blockIdx.x * 128;
    const int wm = (wave & 1) * 64, wn = (wave >> 1) * 64;

    f32x4 acc[4][4];
#pragma unroll
    for (int i = 0; i < 4; ++i)
#pragma unroll
        for (int j = 0; j < 4; ++j) acc[i][j] = (f32x4){0.f, 0.f, 0.f, 0.f};

    const int srow = tid >> 2;       // 0..63
    const int c8   = (tid & 3) * 8;  // 0,8,16,24

    for (int kc = 0; kc < DMODEL; kc += 32) {
#pragma unroll
        for (int p = 0; p < 2; ++p) {
            const int row = srow + 64 * p;
            const float* xa = X + (size_t)(m0 + row) * DMODEL + kc + c8;
            const float4 a0 = *(const float4*)xa;
            const float4 a1 = *(const float4*)(xa + 4);
            union { unsigned short s[8]; uint4 u; } ua;
            ua.s[0] = f2bf(a0.x); ua.s[1] = f2bf(a0.y); ua.s[2] = f2bf(a0.z); ua.s[3] = f2bf(a0.w);
            ua.s[4] = f2bf(a1.x); ua.s[5] = f2bf(a1.y); ua.s[6] = f2bf(a1.z); ua.s[7] = f2bf(a1.w);
            *(uint4*)&As[row * 40 + c8] = ua.u;
            const float* xb = W + (size_t)(n0 + row) * DMODEL + kc + c8;
            const float4 b0 = *(const float4*)xb;
            const float4 b1 = *(const float4*)(xb + 4);
            union { unsigned short s[8]; uint4 u; } ub;
            ub.s[0] = f2bf(b0.x); ub.s[1] = f2bf(b0.y); ub.s[2] = f2bf(b0.z); ub.s[3] = f2bf(b0.w);
            ub.s[4] = f2bf(b1.x); ub.s[5] = f2bf(b1.y); ub.s[6] = f2bf(b1.z); ub.s[7] = f2bf(b1.w);
            *(uint4*)&Bs[row * 40 + c8] = ub.u;
        }
        __syncthreads();

        bf16x8 af[4], bfr[4];
#pragma unroll
        for (int i = 0; i < 4; ++i)
            af[i] = *(const bf16x8*)&As[(wm + i * 16 + ml) * 40 + kq * 8];
#pragma unroll
        for (int j = 0; j < 4; ++j)
            bfr[j] = *(const bf16x8*)&Bs[(wn + j * 16 + ml) * 40 + kq * 8];
#pragma unroll
        for (int i = 0; i < 4; ++i)
#pragma unroll
            for (int j = 0; j < 4; ++j)
                acc[i][j] = MFMA(af[i], bfr[j], acc[i][j]);
        __syncthreads();
    }

    if (z < 2) {
        unsigned short* dst = (z == 0) ? Qd : Kd;
        // RoPE epilogue (C layout: row=(b,l), col=feature), shfl_xor pairs,
        // sin/cos from precomputed table (coalesced float2 loads).
#pragma unroll
        for (int jt = 0; jt < 4; ++jt) {
            const int col = n0 + wn + jt * 16 + ml;
            const float bv = bias[col];
            const int nh = col >> 6, hh = col & 63;
            const int odd = hh & 1;
#pragma unroll
            for (int it = 0; it < 4; ++it) {
#pragma unroll
                for (int r = 0; r < 4; ++r) {
                    const int row = m0 + wm + it * 16 + kq * 4 + r;
                    const int bb = row >> 11, ll = row & 2047;
                    const float v = acc[it][jt][r] + bv;
                    const float partner = __shfl_xor(v, 1);
                    const float2 cs = ropetab[ll * 64 + hh];
                    const float res = odd ? fmaf(v, cs.x, partner * cs.y)
                                          : fmaf(v, cs.x, -partner * cs.y);
                    dst[(((size_t)(bb * NHEAD + nh) * L_SEQ + ll) << 6) + hh] = f2bf(res);
                }
            }
        }
    } else {
        // V: write transposed [b,n,h,l], pack 4 consecutive l per lane (b64).
#pragma unroll
        for (int jt = 0; jt < 4; ++jt) {
            const int col = n0 + wn + jt * 16 + ml;
            const float bv = bias[col];
            const int nh = col >> 6, hh = col & 63;
#pragma unroll
            for (int it = 0; it < 4; ++it) {
                const int rb = m0 + wm + it * 16 + kq * 4;
                const int bb = rb >> 11, ll = rb & 2047;
                union { unsigned short s[4]; uint2 u; } pk;
#pragma unroll
                for (int r = 0; r < 4; ++r) pk.s[r] = f2bf(acc[it][jt][r] + bv);
                *(uint2*)&Vd[(((size_t)bb * NHEAD + nh) * HDIM + hh) * L_SEQ + ll] = pk.u;
            }
        }
    }
}

// ---------------------------------------------------------------------------
// Kernel B: flash attention, S^T / O^T formulation.
// Block = 128 q-rows of one (b,head); 4 waves x 32 q; 64-key tiles.
// Ks/Vs: 64x64 bf16, XOR-swizzled chunks (chunk ^= row&7) -> <=2-way banks.
// Softmax per-lane in log2 domain; only 4 shuffles per (qt,tile).
// Output: hi/lo bf16 planes of O, coalesced via per-wave LDS transpose.
// ---------------------------------------------------------------------------
__global__ __launch_bounds__(256) void attn_kernel(
    const unsigned short* __restrict__ Qr, const unsigned short* __restrict__ Kr,
    const unsigned short* __restrict__ Vt, const unsigned long long* __restrict__ mbits,
    unsigned short* __restrict__ AOhi, unsigned short* __restrict__ AOlo)
{
    __shared__ __align__(16) unsigned short Ks[64 * 64];
    __shared__ __align__(16) unsigned short Vs[64 * 64];
    __shared__ __align__(16) unsigned short Ps[4 * 32 * 72];  // per-wave P / epilogue scratch

    const int tid  = threadIdx.x;
    const int wave = tid >> 6, lane = tid & 63;
    const int ml = lane & 15, kq = lane >> 4;

    // XCD swizzle: 16 q-blocks of the same (b,head) land on the same XCD.
    const int id = blockIdx.x;
    const int xcd = id & 7, slot = id >> 3;
    const int bh = xcd * 4 + (slot & 3);
    const int qb = slot >> 2;
    const int b = bh >> 4, nh = bh & 15;
    const int q0 = qb * 128;

    const unsigned short* Qp = Qr + (size_t)bh * L_SEQ * HDIM;
    const unsigned short* Kp = Kr + (size_t)bh * L_SEQ * HDIM;
    const unsigned short* Vp = Vt + (size_t)bh * HDIM * L_SEQ;

    const int wq = wave * 32;
    bf16x8 qf[2][2];  // [qt][k-chunk]
#pragma unroll
    for (int qt = 0; qt < 2; ++qt)
#pragma unroll
        for (int c = 0; c < 2; ++c)
            qf[qt][c] = *(const bf16x8*)(Qp + (size_t)(q0 + wq + qt * 16 + ml) * HDIM + c * 32 + kq * 8);

    float m2[2] = {-1e30f, -1e30f};
    float li[2] = {0.f, 0.f};
    f32x4 o[2][4];
#pragma unroll
    for (int qt = 0; qt < 2; ++qt)
#pragma unroll
        for (int ht = 0; ht < 4; ++ht) o[qt][ht] = (f32x4){0.f, 0.f, 0.f, 0.f};

    unsigned short* Pw = &Ps[wave * 32 * 72];
    const int srow = tid >> 2;          // 0..63
    const int c0   = (tid & 3) * 2;     // chunk pair
    const float SC = 0.045084230f;      // log2(e) / 32

    for (int kt = 0; kt < L_SEQ / 64; ++kt) {
        __syncthreads();
        {   // stage K [key][h] and V^T [h][key], XOR-swizzled
            const unsigned short* kg = Kp + (size_t)(kt * 64 + srow) * HDIM + c0 * 8;
            const uint4 k0 = *(const uint4*)kg;
            const uint4 k1 = *(const uint4*)(kg + 8);
            *(uint4*)&Ks[srow * 64 + ((c0 ^ (srow & 7)) << 3)]       = k0;
            *(uint4*)&Ks[srow * 64 + (((c0 + 1) ^ (srow & 7)) << 3)] = k1;
            const unsigned short* vg = Vp + (size_t)srow * L_SEQ + kt * 64 + c0 * 8;
            const uint4 v0 = *(const uint4*)vg;
            const uint4 v1 = *(const uint4*)(vg + 8);
            *(uint4*)&Vs[srow * 64 + ((c0 ^ (srow & 7)) << 3)]       = v0;
            *(uint4*)&Vs[srow * 64 + (((c0 + 1) ^ (srow & 7)) << 3)] = v1;
        }
        __syncthreads();

        const unsigned long long mw = mbits[b * 32 + kt];

        // S^T = K * Q^T : [key 64][q 32]; C layout: row=key(kq*4+r), col=q(ml)
        f32x4 st[4][2];
#pragma unroll
        for (int nt = 0; nt < 4; ++nt) {
            const int krow = (nt * 16 + ml) * 64;
            const bf16x8 kf0 = *(const bf16x8*)&Ks[krow + (((0 + kq) ^ (ml & 7)) << 3)];
            const bf16x8 kf1 = *(const bf16x8*)&Ks[krow + (((4 + kq) ^ (ml & 7)) << 3)];
#pragma unroll
            for (int qt = 0; qt < 2; ++qt) {
                f32x4 c = (f32x4){0.f, 0.f, 0.f, 0.f};
                c = MFMA(kf0, qf[qt][0], c);
                c = MFMA(kf1, qf[qt][1], c);
                st[nt][qt] = c;
            }
        }

        // online softmax (log2 domain), P -> LDS (b64 packed)
        float alpha[2];
#pragma unroll
        for (int qt = 0; qt < 2; ++qt) {
            float sv[4][4];
#pragma unroll
            for (int nt = 0; nt < 4; ++nt) {
                const unsigned int nib =
                    ((unsigned int)(mw >> (nt * 16 + kq * 4))) & 0xFu;
#pragma unroll
                for (int r = 0; r < 4; ++r)
                    sv[nt][r] = (nib & (1u << r)) ? -1.0e9f : st[nt][qt][r] * SC;
            }
            float rm = sv[0][0];
#pragma unroll
            for (int nt = 0; nt < 4; ++nt)
#pragma unroll
                for (int r = 0; r < 4; ++r) rm = fmaxf(rm, sv[nt][r]);
            rm = fmaxf(rm, __shfl_xor(rm, 16));
            rm = fmaxf(rm, __shfl_xor(rm, 32));
            const float m2n = fmaxf(m2[qt], rm);
            alpha[qt] = EXP2(m2[qt] - m2n);
            m2[qt] = m2n;
            float rs = 0.f;
#pragma unroll
            for (int nt = 0; nt < 4; ++nt) {
                float p[4];
#pragma unroll
                for (int r = 0; r < 4; ++r) {
                    p[r] = EXP2(sv[nt][r] - m2n);
                    rs += p[r];
                }
                union { unsigned short s[4]; uint2 u; } pk;
#pragma unroll
                for (int r = 0; r < 4; ++r) pk.s[r] = f2bf(p[r]);
                *(uint2*)&Pw[(qt * 16 + ml) * 72 + nt * 16 + kq * 4] = pk.u;
            }
            rs += __shfl_xor(rs, 16);
            rs += __shfl_xor(rs, 32);
            li[qt] = li[qt] * alpha[qt] + rs;
        }

        // O^T += V^T * P : A=V^T frags, B=P frags; no cross-lane alpha needed.
        bf16x8 vf[4][2];
#pragma unroll
        for (int ht = 0; ht < 4; ++ht) {
            const int vrow = (ht * 16 + ml) * 64;
            vf[ht][0] = *(const bf16x8*)&Vs[vrow + (((0 + kq) ^ (ml & 7)) << 3)];
            vf[ht][1] = *(const bf16x8*)&Vs[vrow + (((4 + kq) ^ (ml & 7)) << 3)];
        }
#pragma unroll
        for (int qt = 0; qt < 2; ++qt) {
            const bf16x8 pf0 = *(const bf16x8*)&Pw[(qt * 16 + ml) * 72 + 0 + kq * 8];
            const bf16x8 pf1 = *(const bf16x8*)&Pw[(qt * 16 + ml) * 72 + 32 + kq * 8];
#pragma unroll
            for (int ht = 0; ht < 4; ++ht) {
                f32x4 a = o[qt][ht];
#pragma unroll
                for (int r = 0; r < 4; ++r) a[r] *= alpha[qt];
                a = MFMA(vf[ht][0], pf0, a);
                a = MFMA(vf[ht][1], pf1, a);
                o[qt][ht] = a;
            }
        }
    }

    // Epilogue: O^T lane holds (h = ht*16+kq*4+r, q = qt*16+ml).
    // Per-wave LDS transpose through Pw -> coalesced global stores.
    const float inv[2] = {1.f / li[0], 1.f / li[1]};
    const int qr = lane >> 1, half = lane & 1;
    const size_t gbase = ((size_t)b * L_SEQ + q0 + wq + qr) * DMODEL + nh * 64 + half * 32;

    // hi plane
#pragma unroll
    for (int qt = 0; qt < 2; ++qt)
#pragma unroll
        for (int ht = 0; ht < 4; ++ht) {
            union { unsigned short s[4]; uint2 u; } pk;
#pragma unroll
            for (int r = 0; r < 4; ++r) pk.s[r] = f2bf(o[qt][ht][r] * inv[qt]);
            *(uint2*)&Pw[(qt * 16 + ml) * 72 + ht * 16 + kq * 4] = pk.u;
        }
    {
        const uint4 d0 = *(const uint4*)&Pw[qr * 72 + half * 32];
        const uint4 d1 = *(const uint4*)&Pw[qr * 72 + half * 32 + 8];
        const uint4 d2 = *(const uint4*)&Pw[qr * 72 + half * 32 + 16];
        const uint4 d3 = *(const uint4*)&Pw[qr * 72 + half * 32 + 24];
        *(uint4*)&AOhi[gbase]      = d0;
        *(uint4*)&AOhi[gbase + 8]  = d1;
        *(uint4*)&AOhi[gbase + 16] = d2;
        *(uint4*)&AOhi[gbase + 24] = d3;
    }
    // lo plane
#pragma unroll
    for (int qt = 0; qt < 2; ++qt)
#pragma unroll
        for (int ht = 0; ht < 4; ++ht) {
            union { unsigned short s[4]; uint2 u; } pk;
#pragma unroll
            for (int r = 0; r < 4; ++r) {
                const float v = o[qt][ht][r] * inv[qt];
                const unsigned short h = f2bf(v);
                pk.s[r] = f2bf(v - bf2f(h));
            }
            *(uint2*)&Pw[(qt * 16 + ml) * 72 + ht * 16 + kq * 4] = pk.u;
        }
    {
        const uint4 d0 = *(const uint4*)&Pw[qr * 72 + half * 32];
        const uint4 d1 = *(const uint4*)&Pw[qr * 72 + half * 32 + 8];
        const uint4 d2 = *(const uint4*)&Pw[qr * 72 + half * 32 + 16];
        const uint4 d3 = *(const uint4*)&Pw[qr * 72 + half * 32 + 24];
        *(uint4*)&AOlo[gbase]      = d0;
        *(uint4*)&AOlo[gbase + 8]  = d1;
        *(uint4*)&AOlo[gbase + 16] = d2;
        *(uint4*)&AOlo[gbase + 24] = d3;
    }
}

// ---------------------------------------------------------------------------
// Kernel C: out = AO @ Wo^T + bo, 3-term bf16-split (hi*hi + lo*hi + hi*lo).
// All operands pre-split bf16 planes -> pure b128 staging, no conversion.
// ---------------------------------------------------------------------------
__global__ __launch_bounds__(256) void oproj_kernel(
    const unsigned short* __restrict__ Ahi_g, const unsigned short* __restrict__ Alo_g,
    const unsigned short* __restrict__ Whi_g, const unsigned short* __restrict__ Wlo_g,
    const float* __restrict__ bias, float* __restrict__ out)
{
    __shared__ __align__(16) unsigned short Ah[128 * 40], Al[128 * 40];
    __shared__ __align__(16) unsigned short Bh[128 * 40], Bl[128 * 40];

    const int tid  = threadIdx.x;
    const int wave = tid >> 6, lane = tid & 63;
    const int ml = lane & 15, kq = lane >> 4;
    const int m0 = blockIdx.y * 128, n0 = blockIdx.x * 128;
    const int wm = (wave & 1) * 64, wn = (wave >> 1) * 64;

    f32x4 acc[4][4];
#pragma unroll
    for (int i = 0; i < 4; ++i)
#pragma unroll
        for (int j = 0; j < 4; ++j) acc[i][j] = (f32x4){0.f, 0.f, 0.f, 0.f};

    const int srow = tid >> 2;
    const int c8   = (tid & 3) * 8;

    for (int kc = 0; kc < DMODEL; kc += 32) {
#pragma unroll
        for (int p = 0; p < 2; ++p) {
            const int row = srow + 64 * p;
            const size_t ga = (size_t)(m0 + row) * DMODEL + kc + c8;
            *(uint4*)&Ah[row * 40 + c8] = *(const uint4*)(Ahi_g + ga);
            *(uint4*)&Al[row * 40 + c8] = *(const uint4*)(Alo_g + ga);
            const size_t gb = (size_t)(n0 + row) * DMODEL + kc + c8;
            *(uint4*)&Bh[row * 40 + c8] = *(const uint4*)(Whi_g + gb);
            *(uint4*)&Bl[row * 40 + c8] = *(const uint4*)(Wlo_g + gb);
        }
        __syncthreads();

        bf16x8 ah[4], al[4];
#pragma unroll
        for (int i = 0; i < 4; ++i) {
            ah[i] = *(const bf16x8*)&Ah[(wm + i * 16 + ml) * 40 + kq * 8];
            al[i] = *(const bf16x8*)&Al[(wm + i * 16 + ml) * 40 + kq * 8];
        }
#pragma unroll
        for (int j = 0; j < 4; ++j) {
            const bf16x8 bh_ = *(const bf16x8*)&Bh[(wn + j * 16 + ml) * 40 + kq * 8];
            const bf16x8 bl_ = *(const bf16x8*)&Bl[(wn + j * 16 + ml) * 40 + kq * 8];
#pragma unroll
            for (int i = 0; i < 4; ++i) {
                acc[i][j] = MFMA(ah[i], bh_, acc[i][j]);
                acc[i][j] = MFMA(al[i], bh_, acc[i][j]);
                acc[i][j] = MFMA(ah[i], bl_, acc[i][j]);
            }
        }
        __syncthreads();
    }

#pragma unroll
    for (int jt = 0; jt < 4; ++jt) {
        const int col = n0 + wn + jt * 16 + ml;
        const float bv = bias[col];
#pragma unroll
        for (int it = 0; it < 4; ++it)
#pragma unroll
            for (int r = 0; r < 4; ++r) {
                const int row = m0 + wm + it * 16 + kq * 4 + r;
                out[(size_t)row * DMODEL + col] = acc[it][jt][r] + bv;
            }
    }
}

extern "C" void kernel_launch(void* const* d_in, const int* in_sizes, int n_in,
                              void* d_out, int out_size, void* d_ws, size_t ws_size,
                              hipStream_t stream)
{
    (void)in_sizes; (void)n_in; (void)out_size; (void)ws_size;
    const float* q    = (const float*)d_in[0];
    const float* k    = (const float*)d_in[1];
    const float* v    = (const float*)d_in[2];
    const int*   mask = (const int*)d_in[3];
    const float* Wq   = (const float*)d_in[4];
    const float* bq   = (const float*)d_in[5];
    const float* Wk   = (const float*)d_in[6];
    const float* bk   = (const float*)d_in[7];
    const float* Wv   = (const float*)d_in[8];
    const float* bv   = (const float*)d_in[9];
    const float* Wo   = (const float*)d_in[10];
    const float* bo   = (const float*)d_in[11];
    float* out = (float*)d_out;

    const size_t HE = (size_t)BATCH * NHEAD * L_SEQ * HDIM;  // 4,194,304 elems
    unsigned short* Qr   = (unsigned short*)d_ws;
    unsigned short* Kr   = Qr + HE;
    unsigned short* Vt   = Kr + HE;
    unsigned short* AOhi = Vt + HE;
    unsigned short* AOlo = AOhi + HE;
    unsigned short* Whi  = AOlo + HE;                         // 1M elems
    unsigned short* Wlo  = Whi + (size_t)DMODEL * DMODEL;
    unsigned long long* mbits = (unsigned long long*)(Wlo + (size_t)DMODEL * DMODEL);
    float2* ropetab = (float2*)(mbits + BATCH * L_SEQ / 64);  // 1 MB
    // total ws: 5*8MB + 2*2MB + 8KB + 1MB ~= 45 MB

    maskpack_kernel<<<dim3(BATCH * L_SEQ / 64), dim3(64), 0, stream>>>(mask, mbits);
    wsplit_kernel<<<dim3(DMODEL * DMODEL / 1024), dim3(256), 0, stream>>>(Wo, Whi, Wlo);
    rope_table_kernel<<<dim3(L_SEQ * HDIM / 256), dim3(256), 0, stream>>>(ropetab);

    dim3 blk(256);
    dim3 g1(DMODEL / 128, (BATCH * L_SEQ) / 128, 3);  // 8 x 32 x 3 = 768 blocks
    qkv_kernel<<<g1, blk, 0, stream>>>(q, k, v, Wq, Wk, Wv, bq, bk, bv, ropetab, Qr, Kr, Vt);

    attn_kernel<<<dim3(512), blk, 0, stream>>>(Qr, Kr, Vt, mbits, AOhi, AOlo);

    dim3 g3(DMODEL / 128, (BATCH * L_SEQ) / 128);     // 8 x 32
    oproj_kernel<<<g3, blk, 0, stream>>>(AOhi, AOlo, Whi, Wlo, bo, out);
}

// Round 5
// 292.868 us; speedup vs baseline: 2.0885x; 1.1683x over previous
//
#include <hip/hip_runtime.h>
#include <stdint.h>

#define L_SEQ 2048
#define DMODEL 1024
#define NHEAD 16
#define HDIM 64
#define BATCH 2

typedef __attribute__((ext_vector_type(8))) short bf16x8;
typedef __attribute__((ext_vector_type(4))) float f32x4;

#define MFMA(a, b, c) __builtin_amdgcn_mfma_f32_16x16x32_bf16((a), (b), (c), 0, 0, 0)

#if __has_builtin(__builtin_amdgcn_exp2f)
#define EXP2(x) __builtin_amdgcn_exp2f(x)
#else
#define EXP2(x) exp2f(x)
#endif

__device__ __forceinline__ unsigned short f2bf(float f) {
    unsigned int x = __float_as_uint(f);
    unsigned int r = (x + 0x7fffu + ((x >> 16) & 1u)) >> 16;
    return (unsigned short)r;
}
__device__ __forceinline__ float bf2f(unsigned short h) {
    return __uint_as_float(((unsigned int)h) << 16);
}

// Async global->LDS, 16B per lane. LDS dest = wave-uniform base + lane*16.
__device__ __forceinline__ void gl2lds16(const unsigned short* g, unsigned short* l) {
    __builtin_amdgcn_global_load_lds(
        (const __attribute__((address_space(1))) void*)g,
        (__attribute__((address_space(3))) void*)l, 16, 0, 0);
}

// ---------------------------------------------------------------------------
// Prep 1: pack mask into uint64 bitmasks.
// ---------------------------------------------------------------------------
__global__ void maskpack_kernel(const int* __restrict__ mask,
                                unsigned long long* __restrict__ mbits) {
    const int w = blockIdx.x;
    const unsigned long long bal = __ballot(mask[w * 64 + threadIdx.x] != 0);
    if (threadIdx.x == 0) mbits[w] = bal;
}

// ---------------------------------------------------------------------------
// Prep 2: split Wo into hi/lo bf16 planes.
// ---------------------------------------------------------------------------
__global__ void wsplit_kernel(const float* __restrict__ W,
                              unsigned short* __restrict__ hi,
                              unsigned short* __restrict__ lo) {
    const int i = (blockIdx.x * 256 + threadIdx.x) * 4;
    const float4 v = *(const float4*)(W + i);
    const float f[4] = {v.x, v.y, v.z, v.w};
    union { unsigned short s[4]; uint2 u; } h, l;
#pragma unroll
    for (int r = 0; r < 4; ++r) {
        h.s[r] = f2bf(f[r]);
        l.s[r] = f2bf(f[r] - bf2f(h.s[r]));
    }
    *(uint2*)&hi[i] = h.u;
    *(uint2*)&lo[i] = l.u;
}

// ---------------------------------------------------------------------------
// Prep 3: RoPE table (cos,sin) per (l,h). Keeps libm out of GEMM epilogues.
// ---------------------------------------------------------------------------
__global__ void rope_table_kernel(float2* __restrict__ tab) {
    const int idx = blockIdx.x * 256 + threadIdx.x;
    const int l = idx >> 6, h = idx & 63;
    const float invf = powf(10000.0f, -(float)(h & 62) * (1.0f / 64.0f));
    float sn, cs;
    sincosf((float)l * invf, &sn, &cs);
    tab[idx] = make_float2(cs, sn);
}

// ---------------------------------------------------------------------------
// Prep 4: fp32 -> bf16 conversion of q,k,v (4M each) and Wq,Wk,Wv (1M each).
// Enables pure global_load_lds staging in the GEMMs (halves bytes, kills
// the per-iter f2bf VALU chains).
// ---------------------------------------------------------------------------
__global__ void cvt6_kernel(const float* __restrict__ q, const float* __restrict__ k,
                            const float* __restrict__ v, const float* __restrict__ wq,
                            const float* __restrict__ wk, const float* __restrict__ wv,
                            unsigned short* __restrict__ xb, unsigned short* __restrict__ wb) {
    const int t = blockIdx.y;
    const float* src = (t == 0) ? q : (t == 1) ? k : (t == 2) ? v
                     : (t == 3) ? wq : (t == 4) ? wk : wv;
    unsigned short* dst = (t < 3) ? xb + (size_t)t * 4194304
                                  : wb + (size_t)(t - 3) * 1048576;
    const int n = (t < 3) ? 4194304 : 1048576;
    const int i = (blockIdx.x * 256 + threadIdx.x) * 8;
    if (i >= n) return;
    const float4 a = *(const float4*)(src + i);
    const float4 b = *(const float4*)(src + i + 4);
    union { unsigned short s[8]; uint4 u; } u;
    u.s[0] = f2bf(a.x); u.s[1] = f2bf(a.y); u.s[2] = f2bf(a.z); u.s[3] = f2bf(a.w);
    u.s[4] = f2bf(b.x); u.s[5] = f2bf(b.y); u.s[6] = f2bf(b.z); u.s[7] = f2bf(b.w);
    *(uint4*)(dst + i) = u.u;
}

// ---------------------------------------------------------------------------
// Kernel A: QKV projection, all-bf16 NT GEMM, m97-style global_load_lds
// staging, BK=64, 128x128 tile, un-padded XOR-swizzled LDS.
// Grid: 1D 768, id = bx*96 + z*32 + by  (id%8 == by%8 -> blocks sharing the
// same A-panel colocate on one XCD for L2 reuse).
// ---------------------------------------------------------------------------
__global__ __launch_bounds__(256) void qkv_kernel(
    const unsigned short* __restrict__ Xb, const unsigned short* __restrict__ Wb,
    const float* __restrict__ bq, const float* __restrict__ bk, const float* __restrict__ bv,
    const float2* __restrict__ ropetab,
    unsigned short* __restrict__ Qd, unsigned short* __restrict__ Kd,
    unsigned short* __restrict__ Vd)
{
    const int id = blockIdx.x;
    const int bx = id / 96, rem = id % 96;
    const int z = rem >> 5, by = rem & 31;

    const unsigned short* X = Xb + (size_t)z * (BATCH * L_SEQ * DMODEL);
    const unsigned short* W = Wb + (size_t)z * (DMODEL * DMODEL);
    const float* bias = (z == 0) ? bq : (z == 1) ? bk : bv;

    __shared__ __align__(16) unsigned short As[128 * 64];  // un-padded (DMA dest)
    __shared__ __align__(16) unsigned short Bs[128 * 64];

    const int tid  = threadIdx.x;
    const int wave = tid >> 6, lane = tid & 63;
    const int ml = lane & 15, kq = lane >> 4;
    const int m0 = by * 128, n0 = bx * 128;
    const int wm = (wave & 1) * 64, wn = (wave >> 1) * 64;

    f32x4 acc[4][4];
#pragma unroll
    for (int i = 0; i < 4; ++i)
#pragma unroll
        for (int j = 0; j < 4; ++j) acc[i][j] = (f32x4){0.f, 0.f, 0.f, 0.f};

    // Producer geometry: issue qq covers rows wave*32+qq*8 .. +8.
    // Lane l -> row_local = l>>3, phys chunk = l&7 holds logical chunk
    // (l&7)^((l>>3)&7)  (consumer-side swizzle: phys = logical ^ (row&7)).
    const int prow = wave * 32 + (lane >> 3);
    const int pch  = (lane & 7) ^ ((lane >> 3) & 7);
    const unsigned short* gA = X + (size_t)(m0 + prow) * DMODEL + pch * 8;
    const unsigned short* gB = W + (size_t)(n0 + prow) * DMODEL + pch * 8;
    unsigned short* lA = As + wave * 2048;  // wave*256 slots * 8 shorts
    unsigned short* lB = Bs + wave * 2048;

    for (int kc = 0; kc < DMODEL; kc += 64) {
#pragma unroll
        for (int qq = 0; qq < 4; ++qq) {
            gl2lds16(gA + kc + (size_t)qq * 8 * DMODEL, lA + qq * 512);
            gl2lds16(gB + kc + (size_t)qq * 8 * DMODEL, lB + qq * 512);
        }
        __syncthreads();

        bf16x8 af[2][4], bfv[2][4];
#pragma unroll
        for (int ks = 0; ks < 2; ++ks)
#pragma unroll
            for (int i = 0; i < 4; ++i) {
                const int Ra = wm + i * 16 + ml;
                af[ks][i] = *(const bf16x8*)&As[Ra * 64 + (((ks * 4 + kq) ^ (Ra & 7)) << 3)];
                const int Rb = wn + i * 16 + ml;
                bfv[ks][i] = *(const bf16x8*)&Bs[Rb * 64 + (((ks * 4 + kq) ^ (Rb & 7)) << 3)];
            }
#pragma unroll
        for (int ks = 0; ks < 2; ++ks)
#pragma unroll
            for (int i = 0; i < 4; ++i)
#pragma unroll
                for (int j = 0; j < 4; ++j)
                    acc[i][j] = MFMA(af[ks][i], bfv[ks][j], acc[i][j]);
        __syncthreads();
    }

    if (z < 2) {
        unsigned short* dst = (z == 0) ? Qd : Kd;
#pragma unroll
        for (int jt = 0; jt < 4; ++jt) {
            const int col = n0 + wn + jt * 16 + ml;
            const float bv = bias[col];
            const int nh = col >> 6, hh = col & 63;
            const int odd = hh & 1;
#pragma unroll
            for (int it = 0; it < 4; ++it) {
#pragma unroll
                for (int r = 0; r < 4; ++r) {
                    const int row = m0 + wm + it * 16 + kq * 4 + r;
                    const int bb = row >> 11, ll = row & 2047;
                    const float v = acc[it][jt][r] + bv;
                    const float partner = __shfl_xor(v, 1);
                    const float2 cs = ropetab[ll * 64 + hh];
                    const float res = odd ? fmaf(v, cs.x, partner * cs.y)
                                          : fmaf(v, cs.x, -partner * cs.y);
                    dst[(((size_t)(bb * NHEAD + nh) * L_SEQ + ll) << 6) + hh] = f2bf(res);
                }
            }
        }
    } else {
        // V: write transposed [b,n,h,l], 4 consecutive l per lane (b64).
#pragma unroll
        for (int jt = 0; jt < 4; ++jt) {
            const int col = n0 + wn + jt * 16 + ml;
            const float bv = bias[col];
            const int nh = col >> 6, hh = col & 63;
#pragma unroll
            for (int it = 0; it < 4; ++it) {
                const int rb = m0 + wm + it * 16 + kq * 4;
                const int bb = rb >> 11, ll = rb & 2047;
                union { unsigned short s[4]; uint2 u; } pk;
#pragma unroll
                for (int r = 0; r < 4; ++r) pk.s[r] = f2bf(acc[it][jt][r] + bv);
                *(uint2*)&Vd[(((size_t)bb * NHEAD + nh) * HDIM + hh) * L_SEQ + ll] = pk.u;
            }
        }
    }
}

// ---------------------------------------------------------------------------
// Kernel B: flash attention (UNCHANGED from R4 for attribution).
// ---------------------------------------------------------------------------
__global__ __launch_bounds__(256) void attn_kernel(
    const unsigned short* __restrict__ Qr, const unsigned short* __restrict__ Kr,
    const unsigned short* __restrict__ Vt, const unsigned long long* __restrict__ mbits,
    unsigned short* __restrict__ AOhi, unsigned short* __restrict__ AOlo)
{
    __shared__ __align__(16) unsigned short Ks[64 * 64];
    __shared__ __align__(16) unsigned short Vs[64 * 64];
    __shared__ __align__(16) unsigned short Ps[4 * 32 * 72];

    const int tid  = threadIdx.x;
    const int wave = tid >> 6, lane = tid & 63;
    const int ml = lane & 15, kq = lane >> 4;

    const int id = blockIdx.x;
    const int xcd = id & 7, slot = id >> 3;
    const int bh = xcd * 4 + (slot & 3);
    const int qb = slot >> 2;
    const int b = bh >> 4, nh = bh & 15;
    const int q0 = qb * 128;

    const unsigned short* Qp = Qr + (size_t)bh * L_SEQ * HDIM;
    const unsigned short* Kp = Kr + (size_t)bh * L_SEQ * HDIM;
    const unsigned short* Vp = Vt + (size_t)bh * HDIM * L_SEQ;

    const int wq = wave * 32;
    bf16x8 qf[2][2];
#pragma unroll
    for (int qt = 0; qt < 2; ++qt)
#pragma unroll
        for (int c = 0; c < 2; ++c)
            qf[qt][c] = *(const bf16x8*)(Qp + (size_t)(q0 + wq + qt * 16 + ml) * HDIM + c * 32 + kq * 8);

    float m2[2] = {-1e30f, -1e30f};
    float li[2] = {0.f, 0.f};
    f32x4 o[2][4];
#pragma unroll
    for (int qt = 0; qt < 2; ++qt)
#pragma unroll
        for (int ht = 0; ht < 4; ++ht) o[qt][ht] = (f32x4){0.f, 0.f, 0.f, 0.f};

    unsigned short* Pw = &Ps[wave * 32 * 72];
    const int srow = tid >> 2;
    const int c0   = (tid & 3) * 2;
    const float SC = 0.045084230f;  // log2(e)/32

    for (int kt = 0; kt < L_SEQ / 64; ++kt) {
        __syncthreads();
        {
            const unsigned short* kg = Kp + (size_t)(kt * 64 + srow) * HDIM + c0 * 8;
            const uint4 k0 = *(const uint4*)kg;
            const uint4 k1 = *(const uint4*)(kg + 8);
            *(uint4*)&Ks[srow * 64 + ((c0 ^ (srow & 7)) << 3)]       = k0;
            *(uint4*)&Ks[srow * 64 + (((c0 + 1) ^ (srow & 7)) << 3)] = k1;
            const unsigned short* vg = Vp + (size_t)srow * L_SEQ + kt * 64 + c0 * 8;
            const uint4 v0 = *(const uint4*)vg;
            const uint4 v1 = *(const uint4*)(vg + 8);
            *(uint4*)&Vs[srow * 64 + ((c0 ^ (srow & 7)) << 3)]       = v0;
            *(uint4*)&Vs[srow * 64 + (((c0 + 1) ^ (srow & 7)) << 3)] = v1;
        }
        __syncthreads();

        const unsigned long long mw = mbits[b * 32 + kt];

        f32x4 st[4][2];
#pragma unroll
        for (int nt = 0; nt < 4; ++nt) {
            const int krow = (nt * 16 + ml) * 64;
            const bf16x8 kf0 = *(const bf16x8*)&Ks[krow + (((0 + kq) ^ (ml & 7)) << 3)];
            const bf16x8 kf1 = *(const bf16x8*)&Ks[krow + (((4 + kq) ^ (ml & 7)) << 3)];
#pragma unroll
            for (int qt = 0; qt < 2; ++qt) {
                f32x4 c = (f32x4){0.f, 0.f, 0.f, 0.f};
                c = MFMA(kf0, qf[qt][0], c);
                c = MFMA(kf1, qf[qt][1], c);
                st[nt][qt] = c;
            }
        }

        float alpha[2];
#pragma unroll
        for (int qt = 0; qt < 2; ++qt) {
            float sv[4][4];
#pragma unroll
            for (int nt = 0; nt < 4; ++nt) {
                const unsigned int nib =
                    ((unsigned int)(mw >> (nt * 16 + kq * 4))) & 0xFu;
#pragma unroll
                for (int r = 0; r < 4; ++r)
                    sv[nt][r] = (nib & (1u << r)) ? -1.0e9f : st[nt][qt][r] * SC;
            }
            float rm = sv[0][0];
#pragma unroll
            for (int nt = 0; nt < 4; ++nt)
#pragma unroll
                for (int r = 0; r < 4; ++r) rm = fmaxf(rm, sv[nt][r]);
            rm = fmaxf(rm, __shfl_xor(rm, 16));
            rm = fmaxf(rm, __shfl_xor(rm, 32));
            const float m2n = fmaxf(m2[qt], rm);
            alpha[qt] = EXP2(m2[qt] - m2n);
            m2[qt] = m2n;
            float rs = 0.f;
#pragma unroll
            for (int nt = 0; nt < 4; ++nt) {
                float p[4];
#pragma unroll
                for (int r = 0; r < 4; ++r) {
                    p[r] = EXP2(sv[nt][r] - m2n);
                    rs += p[r];
                }
                union { unsigned short s[4]; uint2 u; } pk;
#pragma unroll
                for (int r = 0; r < 4; ++r) pk.s[r] = f2bf(p[r]);
                *(uint2*)&Pw[(qt * 16 + ml) * 72 + nt * 16 + kq * 4] = pk.u;
            }
            rs += __shfl_xor(rs, 16);
            rs += __shfl_xor(rs, 32);
            li[qt] = li[qt] * alpha[qt] + rs;
        }

        bf16x8 vf[4][2];
#pragma unroll
        for (int ht = 0; ht < 4; ++ht) {
            const int vrow = (ht * 16 + ml) * 64;
            vf[ht][0] = *(const bf16x8*)&Vs[vrow + (((0 + kq) ^ (ml & 7)) << 3)];
            vf[ht][1] = *(const bf16x8*)&Vs[vrow + (((4 + kq) ^ (ml & 7)) << 3)];
        }
#pragma unroll
        for (int qt = 0; qt < 2; ++qt) {
            const bf16x8 pf0 = *(const bf16x8*)&Pw[(qt * 16 + ml) * 72 + 0 + kq * 8];
            const bf16x8 pf1 = *(const bf16x8*)&Pw[(qt * 16 + ml) * 72 + 32 + kq * 8];
#pragma unroll
            for (int ht = 0; ht < 4; ++ht) {
                f32x4 a = o[qt][ht];
#pragma unroll
                for (int r = 0; r < 4; ++r) a[r] *= alpha[qt];
                a = MFMA(vf[ht][0], pf0, a);
                a = MFMA(vf[ht][1], pf1, a);
                o[qt][ht] = a;
            }
        }
    }

    const float inv[2] = {1.f / li[0], 1.f / li[1]};
    const int qr = lane >> 1, half = lane & 1;
    const size_t gbase = ((size_t)b * L_SEQ + q0 + wq + qr) * DMODEL + nh * 64 + half * 32;

#pragma unroll
    for (int qt = 0; qt < 2; ++qt)
#pragma unroll
        for (int ht = 0; ht < 4; ++ht) {
            union { unsigned short s[4]; uint2 u; } pk;
#pragma unroll
            for (int r = 0; r < 4; ++r) pk.s[r] = f2bf(o[qt][ht][r] * inv[qt]);
            *(uint2*)&Pw[(qt * 16 + ml) * 72 + ht * 16 + kq * 4] = pk.u;
        }
    {
        const uint4 d0 = *(const uint4*)&Pw[qr * 72 + half * 32];
        const uint4 d1 = *(const uint4*)&Pw[qr * 72 + half * 32 + 8];
        const uint4 d2 = *(const uint4*)&Pw[qr * 72 + half * 32 + 16];
        const uint4 d3 = *(const uint4*)&Pw[qr * 72 + half * 32 + 24];
        *(uint4*)&AOhi[gbase]      = d0;
        *(uint4*)&AOhi[gbase + 8]  = d1;
        *(uint4*)&AOhi[gbase + 16] = d2;
        *(uint4*)&AOhi[gbase + 24] = d3;
    }
#pragma unroll
    for (int qt = 0; qt < 2; ++qt)
#pragma unroll
        for (int ht = 0; ht < 4; ++ht) {
            union { unsigned short s[4]; uint2 u; } pk;
#pragma unroll
            for (int r = 0; r < 4; ++r) {
                const float v = o[qt][ht][r] * inv[qt];
                const unsigned short h = f2bf(v);
                pk.s[r] = f2bf(v - bf2f(h));
            }
            *(uint2*)&Pw[(qt * 16 + ml) * 72 + ht * 16 + kq * 4] = pk.u;
        }
    {
        const uint4 d0 = *(const uint4*)&Pw[qr * 72 + half * 32];
        const uint4 d1 = *(const uint4*)&Pw[qr * 72 + half * 32 + 8];
        const uint4 d2 = *(const uint4*)&Pw[qr * 72 + half * 32 + 16];
        const uint4 d3 = *(const uint4*)&Pw[qr * 72 + half * 32 + 24];
        *(uint4*)&AOlo[gbase]      = d0;
        *(uint4*)&AOlo[gbase + 8]  = d1;
        *(uint4*)&AOlo[gbase + 16] = d2;
        *(uint4*)&AOlo[gbase + 24] = d3;
    }
}

// ---------------------------------------------------------------------------
// Kernel C: out = AO @ Wo^T + bo, 3-term bf16-split, global_load_lds staging,
// BK=32, 4 LDS planes (32 KB), un-padded XOR-swizzled layout.
// Grid: 1D 256, id = bx*32 + by (id%8 == by%8 -> A-panel XCD colocation).
// ---------------------------------------------------------------------------
__global__ __launch_bounds__(256) void oproj_kernel(
    const unsigned short* __restrict__ Ahi_g, const unsigned short* __restrict__ Alo_g,
    const unsigned short* __restrict__ Whi_g, const unsigned short* __restrict__ Wlo_g,
    const float* __restrict__ bias, float* __restrict__ out)
{
    const int id = blockIdx.x;
    const int bx = id >> 5, by = id & 31;

    __shared__ __align__(16) unsigned short Ah[128 * 32], Al[128 * 32];
    __shared__ __align__(16) unsigned short Bh[128 * 32], Bl[128 * 32];

    const int tid  = threadIdx.x;
    const int wave = tid >> 6, lane = tid & 63;
    const int ml = lane & 15, kq = lane >> 4;
    const int m0 = by * 128, n0 = bx * 128;
    const int wm = (wave & 1) * 64, wn = (wave >> 1) * 64;

    f32x4 acc[4][4];
#pragma unroll
    for (int i = 0; i < 4; ++i)
#pragma unroll
        for (int j = 0; j < 4; ++j) acc[i][j] = (f32x4){0.f, 0.f, 0.f, 0.f};

    // Producer: issue qq (0..1) covers rows wave*32+qq*16 .. +16.
    // Lane l -> row_local = l>>2, phys chunk = l&3 holds logical
    // (l&3)^((l>>3)&3)   (consumer: phys = logical ^ ((row>>1)&3)).
    const int prow = wave * 32 + (lane >> 2);
    const int pch  = (lane & 3) ^ ((lane >> 3) & 3);
    const unsigned short* gAh = Ahi_g + (size_t)(m0 + prow) * DMODEL + pch * 8;
    const unsigned short* gAl = Alo_g + (size_t)(m0 + prow) * DMODEL + pch * 8;
    const unsigned short* gBh = Whi_g + (size_t)(n0 + prow) * DMODEL + pch * 8;
    const unsigned short* gBl = Wlo_g + (size_t)(n0 + prow) * DMODEL + pch * 8;
    unsigned short* lAh = Ah + wave * 1024;  // wave*128 slots * 8 shorts
    unsigned short* lAl = Al + wave * 1024;
    unsigned short* lBh = Bh + wave * 1024;
    unsigned short* lBl = Bl + wave * 1024;

    for (int kc = 0; kc < DMODEL; kc += 32) {
#pragma unroll
        for (int qq = 0; qq < 2; ++qq) {
            const size_t go = kc + (size_t)qq * 16 * DMODEL;
            gl2lds16(gAh + go, lAh + qq * 512);
            gl2lds16(gAl + go, lAl + qq * 512);
            gl2lds16(gBh + go, lBh + qq * 512);
            gl2lds16(gBl + go, lBl + qq * 512);
        }
        __syncthreads();

        bf16x8 ah[4], al[4], bh_[4], bl_[4];
#pragma unroll
        for (int i = 0; i < 4; ++i) {
            const int Ra = wm + i * 16 + ml;
            const int sa = Ra * 32 + ((kq ^ ((Ra >> 1) & 3)) << 3);
            ah[i] = *(const bf16x8*)&Ah[sa];
            al[i] = *(const bf16x8*)&Al[sa];
            const int Rb = wn + i * 16 + ml;
            const int sb = Rb * 32 + ((kq ^ ((Rb >> 1) & 3)) << 3);
            bh_[i] = *(const bf16x8*)&Bh[sb];
            bl_[i] = *(const bf16x8*)&Bl[sb];
        }
#pragma unroll
        for (int i = 0; i < 4; ++i)
#pragma unroll
            for (int j = 0; j < 4; ++j) {
                acc[i][j] = MFMA(ah[i], bh_[j], acc[i][j]);
                acc[i][j] = MFMA(al[i], bh_[j], acc[i][j]);
                acc[i][j] = MFMA(ah[i], bl_[j], acc[i][j]);
            }
        __syncthreads();
    }

#pragma unroll
    for (int jt = 0; jt < 4; ++jt) {
        const int col = n0 + wn + jt * 16 + ml;
        const float bv = bias[col];
#pragma unroll
        for (int it = 0; it < 4; ++it)
#pragma unroll
            for (int r = 0; r < 4; ++r) {
                const int row = m0 + wm + it * 16 + kq * 4 + r;
                out[(size_t)row * DMODEL + col] = acc[it][jt][r] + bv;
            }
    }
}

extern "C" void kernel_launch(void* const* d_in, const int* in_sizes, int n_in,
                              void* d_out, int out_size, void* d_ws, size_t ws_size,
                              hipStream_t stream)
{
    (void)in_sizes; (void)n_in; (void)out_size; (void)ws_size;
    const float* q    = (const float*)d_in[0];
    const float* k    = (const float*)d_in[1];
    const float* v    = (const float*)d_in[2];
    const int*   mask = (const int*)d_in[3];
    const float* Wq   = (const float*)d_in[4];
    const float* bq   = (const float*)d_in[5];
    const float* Wk   = (const float*)d_in[6];
    const float* bk   = (const float*)d_in[7];
    const float* Wv   = (const float*)d_in[8];
    const float* bv   = (const float*)d_in[9];
    const float* Wo   = (const float*)d_in[10];
    const float* bo   = (const float*)d_in[11];
    float* out = (float*)d_out;

    const size_t HE = (size_t)BATCH * NHEAD * L_SEQ * HDIM;   // 4,194,304
    const size_t DD = (size_t)DMODEL * DMODEL;                // 1,048,576
    unsigned short* Xb   = (unsigned short*)d_ws;             // 3*HE = 24 MB
    unsigned short* Wb   = Xb + 3 * HE;                       // 3*DD = 6 MB
    unsigned short* Qr   = Wb + 3 * DD;                       // 8 MB
    unsigned short* Kr   = Qr + HE;
    unsigned short* Vt   = Kr + HE;
    unsigned short* Whi  = Vt + HE;                           // 2 MB
    unsigned short* Wlo  = Whi + DD;
    unsigned long long* mbits = (unsigned long long*)(Wlo + DD);
    float2* ropetab = (float2*)(mbits + BATCH * L_SEQ / 64);  // 1 MB
    // AO planes alias Xb (qkv finishes reading Xb before attn writes them)
    unsigned short* AOhi = Xb;
    unsigned short* AOlo = Xb + HE;
    // total ws: 24 + 6 + 24 + 4 + 1 MB ~= 59 MB

    maskpack_kernel<<<dim3(BATCH * L_SEQ / 64), dim3(64), 0, stream>>>(mask, mbits);
    wsplit_kernel<<<dim3(DD / 1024), dim3(256), 0, stream>>>(Wo, Whi, Wlo);
    rope_table_kernel<<<dim3(L_SEQ * HDIM / 256), dim3(256), 0, stream>>>(ropetab);
    cvt6_kernel<<<dim3(2048, 6), dim3(256), 0, stream>>>(q, k, v, Wq, Wk, Wv, Xb, Wb);

    qkv_kernel<<<dim3(768), dim3(256), 0, stream>>>(Xb, Wb, bq, bk, bv, ropetab, Qr, Kr, Vt);

    attn_kernel<<<dim3(512), dim3(256), 0, stream>>>(Qr, Kr, Vt, mbits, AOhi, AOlo);

    oproj_kernel<<<dim3(256), dim3(256), 0, stream>>>(AOhi, AOlo, Whi, Wlo, bo, out);
}

// Round 6
// 291.582 us; speedup vs baseline: 2.0977x; 1.0044x over previous
//
#include <hip/hip_runtime.h>
#include <stdint.h>

#define L_SEQ 2048
#define DMODEL 1024
#define NHEAD 16
#define HDIM 64
#define BATCH 2

typedef __attribute__((ext_vector_type(8))) short bf16x8;
typedef __attribute__((ext_vector_type(4))) float f32x4;

#define MFMA(a, b, c) __builtin_amdgcn_mfma_f32_16x16x32_bf16((a), (b), (c), 0, 0, 0)

#if __has_builtin(__builtin_amdgcn_exp2f)
#define EXP2(x) __builtin_amdgcn_exp2f(x)
#else
#define EXP2(x) exp2f(x)
#endif

// Round-half-up bf16 (differs from RNE only on exact ties): 2 VALU ops.
__device__ __forceinline__ unsigned short f2bf(float f) {
    return (unsigned short)((__float_as_uint(f) + 0x8000u) >> 16);
}
__device__ __forceinline__ float bf2f(unsigned short h) {
    return __uint_as_float(((unsigned int)h) << 16);
}
// Pack two floats to bf16x2 in 3 VALU ops (2 adds + v_perm).
__device__ __forceinline__ unsigned int pkbf(float a, float b) {
    return __builtin_amdgcn_perm(__float_as_uint(b) + 0x8000u,
                                 __float_as_uint(a) + 0x8000u, 0x07060302u);
}

// Async global->LDS, 16B per lane.
__device__ __forceinline__ void gl2lds16(const unsigned short* g, unsigned short* l) {
    __builtin_amdgcn_global_load_lds(
        (const __attribute__((address_space(1))) void*)g,
        (__attribute__((address_space(3))) void*)l, 16, 0, 0);
}

// ---------------------------------------------------------------------------
// Prep 1: pack mask into uint64 bitmasks.
// ---------------------------------------------------------------------------
__global__ void maskpack_kernel(const int* __restrict__ mask,
                                unsigned long long* __restrict__ mbits) {
    const int w = blockIdx.x;
    const unsigned long long bal = __ballot(mask[w * 64 + threadIdx.x] != 0);
    if (threadIdx.x == 0) mbits[w] = bal;
}

// ---------------------------------------------------------------------------
// Prep 2: split Wo into hi/lo bf16 planes (hi must stay RNE-or-RHU + exact lo).
// ---------------------------------------------------------------------------
__global__ void wsplit_kernel(const float* __restrict__ W,
                              unsigned short* __restrict__ hi,
                              unsigned short* __restrict__ lo) {
    const int i = (blockIdx.x * 256 + threadIdx.x) * 4;
    const float4 v = *(const float4*)(W + i);
    const float f[4] = {v.x, v.y, v.z, v.w};
    union { unsigned short s[4]; uint2 u; } h, l;
#pragma unroll
    for (int r = 0; r < 4; ++r) {
        h.s[r] = f2bf(f[r]);
        l.s[r] = f2bf(f[r] - bf2f(h.s[r]));
    }
    *(uint2*)&hi[i] = h.u;
    *(uint2*)&lo[i] = l.u;
}

// ---------------------------------------------------------------------------
// Prep 3: RoPE table (cos,sin) per (l,h).
// ---------------------------------------------------------------------------
__global__ void rope_table_kernel(float2* __restrict__ tab) {
    const int idx = blockIdx.x * 256 + threadIdx.x;
    const int l = idx >> 6, h = idx & 63;
    const float invf = powf(10000.0f, -(float)(h & 62) * (1.0f / 64.0f));
    float sn, cs;
    sincosf((float)l * invf, &sn, &cs);
    tab[idx] = make_float2(cs, sn);
}

// ---------------------------------------------------------------------------
// Prep 4: fp32 -> bf16 of q,k,v and Wq,Wk,Wv.
// ---------------------------------------------------------------------------
__global__ void cvt6_kernel(const float* __restrict__ q, const float* __restrict__ k,
                            const float* __restrict__ v, const float* __restrict__ wq,
                            const float* __restrict__ wk, const float* __restrict__ wv,
                            unsigned short* __restrict__ xb, unsigned short* __restrict__ wb) {
    const int t = blockIdx.y;
    const float* src = (t == 0) ? q : (t == 1) ? k : (t == 2) ? v
                     : (t == 3) ? wq : (t == 4) ? wk : wv;
    unsigned short* dst = (t < 3) ? xb + (size_t)t * 4194304
                                  : wb + (size_t)(t - 3) * 1048576;
    const int n = (t < 3) ? 4194304 : 1048576;
    const int i = (blockIdx.x * 256 + threadIdx.x) * 8;
    if (i >= n) return;
    const float4 a = *(const float4*)(src + i);
    const float4 b = *(const float4*)(src + i + 4);
    uint4 u;
    u.x = pkbf(a.x, a.y); u.y = pkbf(a.z, a.w);
    u.z = pkbf(b.x, b.y); u.w = pkbf(b.z, b.w);
    *(uint4*)(dst + i) = u;
}

// ---------------------------------------------------------------------------
// Kernel A: QKV projection (unchanged structure from R5).
// ---------------------------------------------------------------------------
__global__ __launch_bounds__(256) void qkv_kernel(
    const unsigned short* __restrict__ Xb, const unsigned short* __restrict__ Wb,
    const float* __restrict__ bq, const float* __restrict__ bk, const float* __restrict__ bv,
    const float2* __restrict__ ropetab,
    unsigned short* __restrict__ Qd, unsigned short* __restrict__ Kd,
    unsigned short* __restrict__ Vd)
{
    const int id = blockIdx.x;
    const int bx = id / 96, rem = id % 96;
    const int z = rem >> 5, by = rem & 31;

    const unsigned short* X = Xb + (size_t)z * (BATCH * L_SEQ * DMODEL);
    const unsigned short* W = Wb + (size_t)z * (DMODEL * DMODEL);
    const float* bias = (z == 0) ? bq : (z == 1) ? bk : bv;

    __shared__ __align__(16) unsigned short As[128 * 64];
    __shared__ __align__(16) unsigned short Bs[128 * 64];

    const int tid  = threadIdx.x;
    const int wave = tid >> 6, lane = tid & 63;
    const int ml = lane & 15, kq = lane >> 4;
    const int m0 = by * 128, n0 = bx * 128;
    const int wm = (wave & 1) * 64, wn = (wave >> 1) * 64;

    f32x4 acc[4][4];
#pragma unroll
    for (int i = 0; i < 4; ++i)
#pragma unroll
        for (int j = 0; j < 4; ++j) acc[i][j] = (f32x4){0.f, 0.f, 0.f, 0.f};

    const int prow = wave * 32 + (lane >> 3);
    const int pch  = (lane & 7) ^ ((lane >> 3) & 7);
    const unsigned short* gA = X + (size_t)(m0 + prow) * DMODEL + pch * 8;
    const unsigned short* gB = W + (size_t)(n0 + prow) * DMODEL + pch * 8;
    unsigned short* lA = As + wave * 2048;
    unsigned short* lB = Bs + wave * 2048;

    for (int kc = 0; kc < DMODEL; kc += 64) {
#pragma unroll
        for (int qq = 0; qq < 4; ++qq) {
            gl2lds16(gA + kc + (size_t)qq * 8 * DMODEL, lA + qq * 512);
            gl2lds16(gB + kc + (size_t)qq * 8 * DMODEL, lB + qq * 512);
        }
        __syncthreads();

        bf16x8 af[2][4], bfv[2][4];
#pragma unroll
        for (int ks = 0; ks < 2; ++ks)
#pragma unroll
            for (int i = 0; i < 4; ++i) {
                const int Ra = wm + i * 16 + ml;
                af[ks][i] = *(const bf16x8*)&As[Ra * 64 + (((ks * 4 + kq) ^ (Ra & 7)) << 3)];
                const int Rb = wn + i * 16 + ml;
                bfv[ks][i] = *(const bf16x8*)&Bs[Rb * 64 + (((ks * 4 + kq) ^ (Rb & 7)) << 3)];
            }
#pragma unroll
        for (int ks = 0; ks < 2; ++ks)
#pragma unroll
            for (int i = 0; i < 4; ++i)
#pragma unroll
                for (int j = 0; j < 4; ++j)
                    acc[i][j] = MFMA(af[ks][i], bfv[ks][j], acc[i][j]);
        __syncthreads();
    }

    if (z < 2) {
        unsigned short* dst = (z == 0) ? Qd : Kd;
#pragma unroll
        for (int jt = 0; jt < 4; ++jt) {
            const int col = n0 + wn + jt * 16 + ml;
            const float bv = bias[col];
            const int nh = col >> 6, hh = col & 63;
            const int odd = hh & 1;
#pragma unroll
            for (int it = 0; it < 4; ++it) {
#pragma unroll
                for (int r = 0; r < 4; ++r) {
                    const int row = m0 + wm + it * 16 + kq * 4 + r;
                    const int bb = row >> 11, ll = row & 2047;
                    const float v = acc[it][jt][r] + bv;
                    const float partner = __shfl_xor(v, 1);
                    const float2 cs = ropetab[ll * 64 + hh];
                    const float res = odd ? fmaf(v, cs.x, partner * cs.y)
                                          : fmaf(v, cs.x, -partner * cs.y);
                    dst[(((size_t)(bb * NHEAD + nh) * L_SEQ + ll) << 6) + hh] = f2bf(res);
                }
            }
        }
    } else {
#pragma unroll
        for (int jt = 0; jt < 4; ++jt) {
            const int col = n0 + wn + jt * 16 + ml;
            const float bv = bias[col];
            const int nh = col >> 6, hh = col & 63;
#pragma unroll
            for (int it = 0; it < 4; ++it) {
                const int rb = m0 + wm + it * 16 + kq * 4;
                const int bb = rb >> 11, ll = rb & 2047;
                uint2 pk;
                pk.x = pkbf(acc[it][jt][0] + bv, acc[it][jt][1] + bv);
                pk.y = pkbf(acc[it][jt][2] + bv, acc[it][jt][3] + bv);
                *(uint2*)&Vd[(((size_t)bb * NHEAD + nh) * HDIM + hh) * L_SEQ + ll] = pk;
            }
        }
    }
}

// ---------------------------------------------------------------------------
// Kernel B: flash attention, S^T/O^T formulation + register-prefetch pipeline
// + v_perm bf16 packing (VALU-bound in R5: 58% VALUBusy, f2bf dominated).
// ---------------------------------------------------------------------------
__global__ __launch_bounds__(256) void attn_kernel(
    const unsigned short* __restrict__ Qr, const unsigned short* __restrict__ Kr,
    const unsigned short* __restrict__ Vt, const unsigned long long* __restrict__ mbits,
    unsigned short* __restrict__ AOhi, unsigned short* __restrict__ AOlo)
{
    __shared__ __align__(16) unsigned short Ks[64 * 64];
    __shared__ __align__(16) unsigned short Vs[64 * 64];
    __shared__ __align__(16) unsigned short Ps[4 * 32 * 72];

    const int tid  = threadIdx.x;
    const int wave = tid >> 6, lane = tid & 63;
    const int ml = lane & 15, kq = lane >> 4;

    const int id = blockIdx.x;
    const int xcd = id & 7, slot = id >> 3;
    const int bh = xcd * 4 + (slot & 3);
    const int qb = slot >> 2;
    const int b = bh >> 4, nh = bh & 15;
    const int q0 = qb * 128;

    const unsigned short* Qp = Qr + (size_t)bh * L_SEQ * HDIM;
    const unsigned short* Kp = Kr + (size_t)bh * L_SEQ * HDIM;
    const unsigned short* Vp = Vt + (size_t)bh * HDIM * L_SEQ;

    const int wq = wave * 32;
    bf16x8 qf[2][2];
#pragma unroll
    for (int qt = 0; qt < 2; ++qt)
#pragma unroll
        for (int c = 0; c < 2; ++c)
            qf[qt][c] = *(const bf16x8*)(Qp + (size_t)(q0 + wq + qt * 16 + ml) * HDIM + c * 32 + kq * 8);

    float m2[2] = {-1e30f, -1e30f};
    float li[2] = {0.f, 0.f};
    f32x4 o[2][4];
#pragma unroll
    for (int qt = 0; qt < 2; ++qt)
#pragma unroll
        for (int ht = 0; ht < 4; ++ht) o[qt][ht] = (f32x4){0.f, 0.f, 0.f, 0.f};

    unsigned short* Pw = &Ps[wave * 32 * 72];
    const int srow = tid >> 2;
    const int c0   = (tid & 3) * 2;
    const float SC = 0.045084230f;  // log2(e)/32

    // Staging addresses (loop-invariant) + initial tile prefetch into regs.
    unsigned short* ksA = &Ks[srow * 64 + ((c0 ^ (srow & 7)) << 3)];
    unsigned short* ksB = &Ks[srow * 64 + (((c0 + 1) ^ (srow & 7)) << 3)];
    unsigned short* vsA = &Vs[srow * 64 + ((c0 ^ (srow & 7)) << 3)];
    unsigned short* vsB = &Vs[srow * 64 + (((c0 + 1) ^ (srow & 7)) << 3)];
    const unsigned short* kg0 = Kp + (size_t)srow * HDIM + c0 * 8;
    const unsigned short* vg0 = Vp + (size_t)srow * L_SEQ + c0 * 8;
    uint4 kA = *(const uint4*)kg0;
    uint4 kB = *(const uint4*)(kg0 + 8);
    uint4 vA = *(const uint4*)vg0;
    uint4 vB = *(const uint4*)(vg0 + 8);
    const unsigned short* kgp = kg0 + 64 * HDIM;
    const unsigned short* vgp = vg0 + 64;

    for (int kt = 0; kt < L_SEQ / 64; ++kt) {
        // drain prefetch regs into LDS
        *(uint4*)ksA = kA;
        *(uint4*)ksB = kB;
        *(uint4*)vsA = vA;
        *(uint4*)vsB = vB;
        __syncthreads();

        const unsigned long long mw = mbits[b * 32 + kt];

        // issue next tile's loads now -> latency overlaps compute below
        if (kt < L_SEQ / 64 - 1) {
            kA = *(const uint4*)kgp;
            kB = *(const uint4*)(kgp + 8);
            kgp += 64 * HDIM;
            vA = *(const uint4*)vgp;
            vB = *(const uint4*)(vgp + 8);
            vgp += 64;
        }

        // S^T = K·Q^T : [key 64][q 32]
        f32x4 st[4][2];
#pragma unroll
        for (int nt = 0; nt < 4; ++nt) {
            const int krow = (nt * 16 + ml) * 64;
            const bf16x8 kf0 = *(const bf16x8*)&Ks[krow + (((0 + kq) ^ (ml & 7)) << 3)];
            const bf16x8 kf1 = *(const bf16x8*)&Ks[krow + (((4 + kq) ^ (ml & 7)) << 3)];
#pragma unroll
            for (int qt = 0; qt < 2; ++qt) {
                f32x4 c = (f32x4){0.f, 0.f, 0.f, 0.f};
                c = MFMA(kf0, qf[qt][0], c);
                c = MFMA(kf1, qf[qt][1], c);
                st[nt][qt] = c;
            }
        }

        // online softmax (log2 domain); P packed via v_perm (3 ops/pair)
        float alpha[2];
#pragma unroll
        for (int qt = 0; qt < 2; ++qt) {
            float sv[4][4];
#pragma unroll
            for (int nt = 0; nt < 4; ++nt) {
                const unsigned int nib =
                    ((unsigned int)(mw >> (nt * 16 + kq * 4))) & 0xFu;
#pragma unroll
                for (int r = 0; r < 4; ++r)
                    sv[nt][r] = (nib & (1u << r)) ? -1.0e9f : st[nt][qt][r] * SC;
            }
            float rm = sv[0][0];
#pragma unroll
            for (int nt = 0; nt < 4; ++nt)
#pragma unroll
                for (int r = 0; r < 4; ++r) rm = fmaxf(rm, sv[nt][r]);
            rm = fmaxf(rm, __shfl_xor(rm, 16));
            rm = fmaxf(rm, __shfl_xor(rm, 32));
            const float m2n = fmaxf(m2[qt], rm);
            alpha[qt] = EXP2(m2[qt] - m2n);
            m2[qt] = m2n;
            float rs = 0.f;
#pragma unroll
            for (int nt = 0; nt < 4; ++nt) {
                float p[4];
#pragma unroll
                for (int r = 0; r < 4; ++r) {
                    p[r] = EXP2(sv[nt][r] - m2n);
                    rs += p[r];
                }
                uint2 pk;
                pk.x = pkbf(p[0], p[1]);
                pk.y = pkbf(p[2], p[3]);
                *(uint2*)&Pw[(qt * 16 + ml) * 72 + nt * 16 + kq * 4] = pk;
            }
            rs += __shfl_xor(rs, 16);
            rs += __shfl_xor(rs, 32);
            li[qt] = li[qt] * alpha[qt] + rs;
        }

        // O^T += V^T·P
        bf16x8 vf[4][2];
#pragma unroll
        for (int ht = 0; ht < 4; ++ht) {
            const int vrow = (ht * 16 + ml) * 64;
            vf[ht][0] = *(const bf16x8*)&Vs[vrow + (((0 + kq) ^ (ml & 7)) << 3)];
            vf[ht][1] = *(const bf16x8*)&Vs[vrow + (((4 + kq) ^ (ml & 7)) << 3)];
        }
#pragma unroll
        for (int qt = 0; qt < 2; ++qt) {
            const bf16x8 pf0 = *(const bf16x8*)&Pw[(qt * 16 + ml) * 72 + 0 + kq * 8];
            const bf16x8 pf1 = *(const bf16x8*)&Pw[(qt * 16 + ml) * 72 + 32 + kq * 8];
#pragma unroll
            for (int ht = 0; ht < 4; ++ht) {
                f32x4 a = o[qt][ht];
#pragma unroll
                for (int r = 0; r < 4; ++r) a[r] *= alpha[qt];
                a = MFMA(vf[ht][0], pf0, a);
                a = MFMA(vf[ht][1], pf1, a);
                o[qt][ht] = a;
            }
        }
        __syncthreads();
    }

    // Epilogue: LDS transpose -> coalesced hi/lo plane stores.
    const float inv[2] = {1.f / li[0], 1.f / li[1]};
    const int qr = lane >> 1, half = lane & 1;
    const size_t gbase = ((size_t)b * L_SEQ + q0 + wq + qr) * DMODEL + nh * 64 + half * 32;

#pragma unroll
    for (int qt = 0; qt < 2; ++qt)
#pragma unroll
        for (int ht = 0; ht < 4; ++ht) {
            uint2 pk;
            pk.x = pkbf(o[qt][ht][0] * inv[qt], o[qt][ht][1] * inv[qt]);
            pk.y = pkbf(o[qt][ht][2] * inv[qt], o[qt][ht][3] * inv[qt]);
            *(uint2*)&Pw[(qt * 16 + ml) * 72 + ht * 16 + kq * 4] = pk;
        }
    {
        const uint4 d0 = *(const uint4*)&Pw[qr * 72 + half * 32];
        const uint4 d1 = *(const uint4*)&Pw[qr * 72 + half * 32 + 8];
        const uint4 d2 = *(const uint4*)&Pw[qr * 72 + half * 32 + 16];
        const uint4 d3 = *(const uint4*)&Pw[qr * 72 + half * 32 + 24];
        *(uint4*)&AOhi[gbase]      = d0;
        *(uint4*)&AOhi[gbase + 8]  = d1;
        *(uint4*)&AOhi[gbase + 16] = d2;
        *(uint4*)&AOhi[gbase + 24] = d3;
    }
    __syncthreads();
#pragma unroll
    for (int qt = 0; qt < 2; ++qt)
#pragma unroll
        for (int ht = 0; ht < 4; ++ht) {
            float lo[4];
#pragma unroll
            for (int r = 0; r < 4; ++r) {
                const float v = o[qt][ht][r] * inv[qt];
                const float hf = __uint_as_float((__float_as_uint(v) + 0x8000u) & 0xffff0000u);
                lo[r] = v - hf;
            }
            uint2 pk;
            pk.x = pkbf(lo[0], lo[1]);
            pk.y = pkbf(lo[2], lo[3]);
            *(uint2*)&Pw[(qt * 16 + ml) * 72 + ht * 16 + kq * 4] = pk;
        }
    {
        const uint4 d0 = *(const uint4*)&Pw[qr * 72 + half * 32];
        const uint4 d1 = *(const uint4*)&Pw[qr * 72 + half * 32 + 8];
        const uint4 d2 = *(const uint4*)&Pw[qr * 72 + half * 32 + 16];
        const uint4 d3 = *(const uint4*)&Pw[qr * 72 + half * 32 + 24];
        *(uint4*)&AOlo[gbase]      = d0;
        *(uint4*)&AOlo[gbase + 8]  = d1;
        *(uint4*)&AOlo[gbase + 16] = d2;
        *(uint4*)&AOlo[gbase + 24] = d3;
    }
}

// ---------------------------------------------------------------------------
// Kernel C: out = AO @ Wo^T + bo (unchanged structure from R5).
// ---------------------------------------------------------------------------
__global__ __launch_bounds__(256) void oproj_kernel(
    const unsigned short* __restrict__ Ahi_g, const unsigned short* __restrict__ Alo_g,
    const unsigned short* __restrict__ Whi_g, const unsigned short* __restrict__ Wlo_g,
    const float* __restrict__ bias, float* __restrict__ out)
{
    const int id = blockIdx.x;
    const int bx = id >> 5, by = id & 31;

    __shared__ __align__(16) unsigned short Ah[128 * 32], Al[128 * 32];
    __shared__ __align__(16) unsigned short Bh[128 * 32], Bl[128 * 32];

    const int tid  = threadIdx.x;
    const int wave = tid >> 6, lane = tid & 63;
    const int ml = lane & 15, kq = lane >> 4;
    const int m0 = by * 128, n0 = bx * 128;
    const int wm = (wave & 1) * 64, wn = (wave >> 1) * 64;

    f32x4 acc[4][4];
#pragma unroll
    for (int i = 0; i < 4; ++i)
#pragma unroll
        for (int j = 0; j < 4; ++j) acc[i][j] = (f32x4){0.f, 0.f, 0.f, 0.f};

    const int prow = wave * 32 + (lane >> 2);
    const int pch  = (lane & 3) ^ ((lane >> 3) & 3);
    const unsigned short* gAh = Ahi_g + (size_t)(m0 + prow) * DMODEL + pch * 8;
    const unsigned short* gAl = Alo_g + (size_t)(m0 + prow) * DMODEL + pch * 8;
    const unsigned short* gBh = Whi_g + (size_t)(n0 + prow) * DMODEL + pch * 8;
    const unsigned short* gBl = Wlo_g + (size_t)(n0 + prow) * DMODEL + pch * 8;
    unsigned short* lAh = Ah + wave * 1024;
    unsigned short* lAl = Al + wave * 1024;
    unsigned short* lBh = Bh + wave * 1024;
    unsigned short* lBl = Bl + wave * 1024;

    for (int kc = 0; kc < DMODEL; kc += 32) {
#pragma unroll
        for (int qq = 0; qq < 2; ++qq) {
            const size_t go = kc + (size_t)qq * 16 * DMODEL;
            gl2lds16(gAh + go, lAh + qq * 512);
            gl2lds16(gAl + go, lAl + qq * 512);
            gl2lds16(gBh + go, lBh + qq * 512);
            gl2lds16(gBl + go, lBl + qq * 512);
        }
        __syncthreads();

        bf16x8 ah[4], al[4], bh_[4], bl_[4];
#pragma unroll
        for (int i = 0; i < 4; ++i) {
            const int Ra = wm + i * 16 + ml;
            const int sa = Ra * 32 + ((kq ^ ((Ra >> 1) & 3)) << 3);
            ah[i] = *(const bf16x8*)&Ah[sa];
            al[i] = *(const bf16x8*)&Al[sa];
            const int Rb = wn + i * 16 + ml;
            const int sb = Rb * 32 + ((kq ^ ((Rb >> 1) & 3)) << 3);
            bh_[i] = *(const bf16x8*)&Bh[sb];
            bl_[i] = *(const bf16x8*)&Bl[sb];
        }
#pragma unroll
        for (int i = 0; i < 4; ++i)
#pragma unroll
            for (int j = 0; j < 4; ++j) {
                acc[i][j] = MFMA(ah[i], bh_[j], acc[i][j]);
                acc[i][j] = MFMA(al[i], bh_[j], acc[i][j]);
                acc[i][j] = MFMA(ah[i], bl_[j], acc[i][j]);
            }
        __syncthreads();
    }

#pragma unroll
    for (int jt = 0; jt < 4; ++jt) {
        const int col = n0 + wn + jt * 16 + ml;
        const float bv = bias[col];
#pragma unroll
        for (int it = 0; it < 4; ++it)
#pragma unroll
            for (int r = 0; r < 4; ++r) {
                const int row = m0 + wm + it * 16 + kq * 4 + r;
                out[(size_t)row * DMODEL + col] = acc[it][jt][r] + bv;
            }
    }
}

extern "C" void kernel_launch(void* const* d_in, const int* in_sizes, int n_in,
                              void* d_out, int out_size, void* d_ws, size_t ws_size,
                              hipStream_t stream)
{
    (void)in_sizes; (void)n_in; (void)out_size; (void)ws_size;
    const float* q    = (const float*)d_in[0];
    const float* k    = (const float*)d_in[1];
    const float* v    = (const float*)d_in[2];
    const int*   mask = (const int*)d_in[3];
    const float* Wq   = (const float*)d_in[4];
    const float* bq   = (const float*)d_in[5];
    const float* Wk   = (const float*)d_in[6];
    const float* bk   = (const float*)d_in[7];
    const float* Wv   = (const float*)d_in[8];
    const float* bv   = (const float*)d_in[9];
    const float* Wo   = (const float*)d_in[10];
    const float* bo   = (const float*)d_in[11];
    float* out = (float*)d_out;

    const size_t HE = (size_t)BATCH * NHEAD * L_SEQ * HDIM;   // 4,194,304
    const size_t DD = (size_t)DMODEL * DMODEL;                // 1,048,576
    unsigned short* Xb   = (unsigned short*)d_ws;             // 24 MB
    unsigned short* Wb   = Xb + 3 * HE;                       // 6 MB
    unsigned short* Qr   = Wb + 3 * DD;
    unsigned short* Kr   = Qr + HE;
    unsigned short* Vt   = Kr + HE;
    unsigned short* Whi  = Vt + HE;
    unsigned short* Wlo  = Whi + DD;
    unsigned long long* mbits = (unsigned long long*)(Wlo + DD);
    float2* ropetab = (float2*)(mbits + BATCH * L_SEQ / 64);
    unsigned short* AOhi = Xb;          // alias Xb (qkv done reading)
    unsigned short* AOlo = Xb + HE;

    maskpack_kernel<<<dim3(BATCH * L_SEQ / 64), dim3(64), 0, stream>>>(mask, mbits);
    wsplit_kernel<<<dim3(DD / 1024), dim3(256), 0, stream>>>(Wo, Whi, Wlo);
    rope_table_kernel<<<dim3(L_SEQ * HDIM / 256), dim3(256), 0, stream>>>(ropetab);
    cvt6_kernel<<<dim3(2048, 6), dim3(256), 0, stream>>>(q, k, v, Wq, Wk, Wv, Xb, Wb);

    qkv_kernel<<<dim3(768), dim3(256), 0, stream>>>(Xb, Wb, bq, bk, bv, ropetab, Qr, Kr, Vt);

    attn_kernel<<<dim3(512), dim3(256), 0, stream>>>(Qr, Kr, Vt, mbits, AOhi, AOlo);

    oproj_kernel<<<dim3(256), dim3(256), 0, stream>>>(AOhi, AOlo, Whi, Wlo, bo, out);
}